// Round 1
// baseline (3631.268 us; speedup 1.0000x reference)
//
#include <hip/hip_runtime.h>
#include <hip/hip_bf16.h>

// BlocksCore forward, f32 correctness-first pipeline.
// B=4096, NINP=512, NHID=2048, NB=8, BS=256, ATT_OUT=1024, TOPK=4, DK_I=64, NH=4, DK_M=16

#define B_SZ 4096
#define NINP 512
#define NHID 2048
#define NB 8
#define BSZ 256
#define ATT_OUT 1024

__device__ __forceinline__ float sigf(float x) { return 1.0f / (1.0f + expf(-x)); }

// ---------------------------------------------------------------------------
// Generic tiled f32 GEMM: C[m,n] = sum_k A[m,k]*B[k,n]
// A row-major (lda), B row-major K x N (ldb), C row-major (ldc).
// blockIdx.z applies element offsets (block-diagonal / sliced weights).
// Tile 64x64, BK=16, 256 threads, 4x4 per thread. All dims assumed divisible.
// ---------------------------------------------------------------------------
__global__ __launch_bounds__(256) void gemm_f32(
    const float* __restrict__ A, const float* __restrict__ B, float* __restrict__ C,
    int K, int lda, int ldb, int ldc,
    long aOffZ, long bOffZ, long cOffZ)
{
    const int z = blockIdx.z;
    A += (long)z * aOffZ;
    B += (long)z * bOffZ;
    C += (long)z * cOffZ;
    const int n0 = blockIdx.x * 64;
    const int m0 = blockIdx.y * 64;

    __shared__ float As[64][17];
    __shared__ float Bs[16][65];

    const int t = threadIdx.x;
    const int ty = t >> 4;   // 0..15
    const int tx = t & 15;   // 0..15

    float acc[4][4] = {};

    for (int k0 = 0; k0 < K; k0 += 16) {
        // load A tile 64x16 (float4 per thread)
        {
            int m = t >> 2, kk = (t & 3) << 2;
            float4 av = *reinterpret_cast<const float4*>(&A[(long)(m0 + m) * lda + k0 + kk]);
            As[m][kk] = av.x; As[m][kk + 1] = av.y; As[m][kk + 2] = av.z; As[m][kk + 3] = av.w;
        }
        // load B tile 16x64
        {
            int kr = t >> 4, c = (t & 15) << 2;
            float4 bv = *reinterpret_cast<const float4*>(&B[(long)(k0 + kr) * ldb + n0 + c]);
            Bs[kr][c] = bv.x; Bs[kr][c + 1] = bv.y; Bs[kr][c + 2] = bv.z; Bs[kr][c + 3] = bv.w;
        }
        __syncthreads();
        #pragma unroll
        for (int kk = 0; kk < 16; ++kk) {
            float a[4], b[4];
            #pragma unroll
            for (int i = 0; i < 4; ++i) a[i] = As[ty * 4 + i][kk];
            #pragma unroll
            for (int j = 0; j < 4; ++j) b[j] = Bs[kk][tx * 4 + j];
            #pragma unroll
            for (int i = 0; i < 4; ++i)
                #pragma unroll
                for (int j = 0; j < 4; ++j) acc[i][j] += a[i] * b[j];
        }
        __syncthreads();
    }
    #pragma unroll
    for (int i = 0; i < 4; ++i)
        #pragma unroll
        for (int j = 0; j < 4; ++j)
            C[(long)(m0 + ty * 4 + i) * ldc + n0 + tx * 4 + j] = acc[i][j];
}

// ---------------------------------------------------------------------------
// s1 = (q . k1)/8 per (b, kb); w = sigmoid(s1); mblk via exact top-k ranking;
// writes mask region of d_out. One wave per batch row.
// ---------------------------------------------------------------------------
__global__ __launch_bounds__(256) void s1_mask_kernel(
    const float* __restrict__ q, const float* __restrict__ k1,
    float* __restrict__ w_ws, float* __restrict__ mblk,
    float* __restrict__ mask_out)
{
    const int wave = threadIdx.x >> 6;
    const int lane = threadIdx.x & 63;
    const int b = blockIdx.x * 4 + wave;

    float p[8];
    const float kv = k1[(long)b * 64 + lane];
    #pragma unroll
    for (int kb = 0; kb < 8; ++kb)
        p[kb] = q[(long)b * 512 + kb * 64 + lane] * kv;

    #pragma unroll
    for (int off = 1; off < 64; off <<= 1) {
        #pragma unroll
        for (int kb = 0; kb < 8; ++kb) p[kb] += __shfl_xor(p[kb], off);
    }

    float s[8], mv[8];
    #pragma unroll
    for (int kb = 0; kb < 8; ++kb) s[kb] = p[kb] * 0.125f;

    // mask 0 goes to the 4 smallest s1 (== 4 largest sigma(-s1)); ties -> lower
    // index gets mask 0 first (jax top_k tie-break).
    #pragma unroll
    for (int j = 0; j < 8; ++j) {
        int r = 0;
        #pragma unroll
        for (int i = 0; i < 8; ++i)
            r += (s[i] < s[j]) || (s[i] == s[j] && i < j);
        mv[j] = (r >= 4) ? 1.0f : 0.0f;
    }
    if (lane < 8) {
        w_ws[(long)b * 8 + lane] = sigf(s[lane]);
        mblk[(long)b * 8 + lane] = mv[lane];
    }
    // write repeated mask (2048 per row)
    #pragma unroll
    for (int it = 0; it < 32; ++it) {
        int idx = it * 64 + lane;
        mask_out[(long)b * 2048 + idx] = mv[idx >> 8];
    }
}

// ---------------------------------------------------------------------------
// Fused gates GEMM + LSTM.
// gates[b,kb,seg*256+j] = w[b,kb]*sum_d v1[b,d]*Wih[kb,seg*256+j,d]
//                       + sum_h hx[b,kb*256+h]*Whh[kb,seg*256+j,h] + b_ih + b_hh
// Then c_new/h_new written straight into d_out's cx/hx slots.
// Block: 32 batch rows x 64 j-cols x 4 segments. 256 threads (8x32), 4x2 per seg.
// ---------------------------------------------------------------------------
#define GBK 32
__global__ __launch_bounds__(256) void gates_lstm_kernel(
    const float* __restrict__ v1, const float* __restrict__ hx,
    const float* __restrict__ cx,
    const float* __restrict__ Wih, const float* __restrict__ Whh,
    const float* __restrict__ b_ih, const float* __restrict__ b_hh,
    const float* __restrict__ w_ws,
    float* __restrict__ h_out, float* __restrict__ c_out)
{
    const int mb = blockIdx.x * 32;
    const int j0 = blockIdx.y * 64;
    const int kb = blockIdx.z;

    __shared__ float As[32][GBK + 1];
    __shared__ float Bs[4][GBK][65];
    __shared__ float wv[32];

    const int t = threadIdx.x;
    if (t < 32) wv[t] = w_ws[(long)(mb + t) * 8 + kb];
    __syncthreads();

    const int ty = t >> 5;  // 0..7 (row group, 4 rows each)
    const int tx = t & 31;  // 0..31 (col group, 2 cols each)

    float acc[4][4][2] = {};

    // ---- phase 1: K=1024 over v1 * Wih^T (A scaled by w) ----
    const float* Wb = Wih + (long)kb * 1024 * 1024;
    for (int k0 = 0; k0 < 1024; k0 += GBK) {
        {
            int m = t >> 3, kk = (t & 7) << 2;
            float4 av = *reinterpret_cast<const float4*>(&v1[(long)(mb + m) * 1024 + k0 + kk]);
            float sc = wv[m];
            As[m][kk] = av.x * sc; As[m][kk + 1] = av.y * sc;
            As[m][kk + 2] = av.z * sc; As[m][kk + 3] = av.w * sc;
        }
        #pragma unroll
        for (int u = 0; u < 8; ++u) {
            int f = t + 256 * u;           // 0..2047 float4 slots
            int seg = f >> 9;
            int rem = f & 511;
            int c = rem >> 3;
            int kk = (rem & 7) << 2;
            float4 bv = *reinterpret_cast<const float4*>(
                &Wb[(long)(seg * 256 + j0 + c) * 1024 + k0 + kk]);
            Bs[seg][kk][c] = bv.x; Bs[seg][kk + 1][c] = bv.y;
            Bs[seg][kk + 2][c] = bv.z; Bs[seg][kk + 3][c] = bv.w;
        }
        __syncthreads();
        #pragma unroll
        for (int kk = 0; kk < GBK; ++kk) {
            float a[4];
            #pragma unroll
            for (int i = 0; i < 4; ++i) a[i] = As[ty * 4 + i][kk];
            #pragma unroll
            for (int seg = 0; seg < 4; ++seg) {
                float b0 = Bs[seg][kk][tx * 2];
                float b1 = Bs[seg][kk][tx * 2 + 1];
                #pragma unroll
                for (int i = 0; i < 4; ++i) {
                    acc[seg][i][0] += a[i] * b0;
                    acc[seg][i][1] += a[i] * b1;
                }
            }
        }
        __syncthreads();
    }

    // ---- phase 2: K=256 over hx-block * Whh^T ----
    const float* Wb2 = Whh + (long)kb * 1024 * 256;
    for (int k0 = 0; k0 < 256; k0 += GBK) {
        {
            int m = t >> 3, kk = (t & 7) << 2;
            float4 av = *reinterpret_cast<const float4*>(
                &hx[(long)(mb + m) * 2048 + kb * 256 + k0 + kk]);
            As[m][kk] = av.x; As[m][kk + 1] = av.y;
            As[m][kk + 2] = av.z; As[m][kk + 3] = av.w;
        }
        #pragma unroll
        for (int u = 0; u < 8; ++u) {
            int f = t + 256 * u;
            int seg = f >> 9;
            int rem = f & 511;
            int c = rem >> 3;
            int kk = (rem & 7) << 2;
            float4 bv = *reinterpret_cast<const float4*>(
                &Wb2[(long)(seg * 256 + j0 + c) * 256 + k0 + kk]);
            Bs[seg][kk][c] = bv.x; Bs[seg][kk + 1][c] = bv.y;
            Bs[seg][kk + 2][c] = bv.z; Bs[seg][kk + 3][c] = bv.w;
        }
        __syncthreads();
        #pragma unroll
        for (int kk = 0; kk < GBK; ++kk) {
            float a[4];
            #pragma unroll
            for (int i = 0; i < 4; ++i) a[i] = As[ty * 4 + i][kk];
            #pragma unroll
            for (int seg = 0; seg < 4; ++seg) {
                float b0 = Bs[seg][kk][tx * 2];
                float b1 = Bs[seg][kk][tx * 2 + 1];
                #pragma unroll
                for (int i = 0; i < 4; ++i) {
                    acc[seg][i][0] += a[i] * b0;
                    acc[seg][i][1] += a[i] * b1;
                }
            }
        }
        __syncthreads();
    }

    // ---- bias + LSTM + store ----
    #pragma unroll
    for (int jj = 0; jj < 2; ++jj) {
        const int j = j0 + tx * 2 + jj;
        float bi[4];
        #pragma unroll
        for (int seg = 0; seg < 4; ++seg)
            bi[seg] = b_ih[(long)kb * 1024 + seg * 256 + j] +
                      b_hh[(long)kb * 1024 + seg * 256 + j];
        #pragma unroll
        for (int i = 0; i < 4; ++i) {
            const long row = mb + ty * 4 + i;
            const long idx = row * 2048 + kb * 256 + j;
            float ig = acc[0][i][jj] + bi[0];
            float fg = acc[1][i][jj] + bi[1];
            float gg = acc[2][i][jj] + bi[2];
            float og = acc[3][i][jj] + bi[3];
            float c_old = cx[idx];
            float cn = sigf(fg) * c_old + sigf(ig) * tanhf(gg);
            float hn = sigf(og) * tanhf(cn);
            h_out[idx] = hn;
            c_out[idx] = cn;
        }
    }
}

// ---------------------------------------------------------------------------
// Inner NBxNB attention (NH=4 heads, DK_M=16). One thread per (b, q_kb, h).
// ---------------------------------------------------------------------------
__global__ __launch_bounds__(256) void attn_m_kernel(
    const float* __restrict__ qm, const float* __restrict__ km,
    const float* __restrict__ vm, float* __restrict__ o)
{
    const int tid = blockIdx.x * 256 + threadIdx.x;  // b*32 + qkb*4 + h
    const int b = tid >> 5;
    const int qkb = (tid >> 2) & 7;
    const int h = tid & 3;

    const float* qp = qm + (long)b * 512 + qkb * 64 + h * 16;
    float qv[16];
    #pragma unroll
    for (int e = 0; e < 16; ++e) qv[e] = qp[e];

    float sc[8];
    float mx = -1e30f;
    #pragma unroll
    for (int kk = 0; kk < 8; ++kk) {
        const float* kp = km + (long)b * 512 + kk * 64 + h * 16;
        float s = 0.f;
        #pragma unroll
        for (int e = 0; e < 16; ++e) s += qv[e] * kp[e];
        s *= 0.25f;
        sc[kk] = s;
        mx = fmaxf(mx, s);
    }
    float den = 0.f;
    #pragma unroll
    for (int kk = 0; kk < 8; ++kk) { sc[kk] = expf(sc[kk] - mx); den += sc[kk]; }
    const float inv = 1.0f / den;

    float ov[16] = {};
    #pragma unroll
    for (int kk = 0; kk < 8; ++kk) {
        const float pw = sc[kk] * inv;
        const float* vp = vm + (long)b * 512 + kk * 64 + h * 16;
        #pragma unroll
        for (int e = 0; e < 16; ++e) ov[e] += pw * vp[e];
    }
    float* op = o + (long)b * 512 + qkb * 64 + h * 16;
    #pragma unroll
    for (int e = 0; e < 16; ++e) op[e] = ov[e];
}

// ---------------------------------------------------------------------------
// att_out = sigmoid(o@gate_w^T + gate_b) * tanh(o@fc_w^T + fc_b)
// h_final = h_new + att_out; masked blend into outputs.
// One block processes 8 (b,kb) pairs; 256 threads = j dim.
// ---------------------------------------------------------------------------
__global__ __launch_bounds__(256) void final_kernel(
    const float* __restrict__ o,
    const float* __restrict__ gate_w, const float* __restrict__ gate_b,
    const float* __restrict__ fc_w, const float* __restrict__ fc_b,
    const float* __restrict__ mblk,
    const float* __restrict__ hx, const float* __restrict__ cx,
    float* __restrict__ h_out, float* __restrict__ c_out)
{
    __shared__ float osh[64];
    const int j = threadIdx.x;
    for (int it = 0; it < 8; ++it) {
        const int p = blockIdx.x * 8 + it;
        const int b = p >> 3;
        const int kb = p & 7;
        __syncthreads();
        if (j < 64) osh[j] = o[(long)b * 512 + kb * 64 + j];
        __syncthreads();

        float g1 = gate_b[j];
        float g2 = fc_b[j];
        #pragma unroll 8
        for (int e = 0; e < 64; ++e) {
            const float ov = osh[e];
            g1 += ov * gate_w[j * 64 + e];
            g2 += ov * fc_w[j * 64 + e];
        }
        const float att = sigf(g1) * tanhf(g2);
        const long idx = (long)b * 2048 + kb * 256 + j;
        const float m = mblk[(long)b * 8 + kb];
        const float hn = h_out[idx] + att;
        h_out[idx] = (m != 0.0f) ? hn : hx[idx];
        c_out[idx] = (m != 0.0f) ? c_out[idx] : cx[idx];
    }
}

// ---------------------------------------------------------------------------
extern "C" void kernel_launch(void* const* d_in, const int* in_sizes, int n_in,
                              void* d_out, int out_size, void* d_ws, size_t ws_size,
                              hipStream_t stream) {
    const float* inp    = (const float*)d_in[0];
    const float* hx     = (const float*)d_in[1];
    const float* cx     = (const float*)d_in[2];
    const float* Wq_i   = (const float*)d_in[3];
    const float* Wk_i   = (const float*)d_in[4];
    const float* Wv_i   = (const float*)d_in[5];
    const float* Wq_m   = (const float*)d_in[6];
    const float* Wk_m   = (const float*)d_in[7];
    const float* Wv_m   = (const float*)d_in[8];
    const float* fc_w   = (const float*)d_in[9];
    const float* fc_b   = (const float*)d_in[10];
    const float* gate_w = (const float*)d_in[11];
    const float* gate_b = (const float*)d_in[12];
    const float* Wih    = (const float*)d_in[13];
    const float* Whh    = (const float*)d_in[14];
    const float* b_ih   = (const float*)d_in[15];
    const float* b_hh   = (const float*)d_in[16];

    float* out  = (float*)d_out;
    float* h_out    = out;                       // B*2048 (h_new, then hx_out)
    float* c_out    = out + (long)B_SZ * 2048;   // B*2048 (c_new, then cx_out)
    float* mask_out = out + (long)2 * B_SZ * 2048;

    // workspace layout (floats); total ~60 MB
    float* ws   = (float*)d_ws;
    float* k1   = ws;                       // B*64
    float* q    = k1 + (long)B_SZ * 64;     // B*512
    float* w_ws = q + (long)B_SZ * 512;     // B*8
    float* mblk = w_ws + (long)B_SZ * 8;    // B*8
    float* v1   = mblk + (long)B_SZ * 8;    // B*1024
    float* qm   = v1 + (long)B_SZ * 1024;   // B*512
    float* km   = qm + (long)B_SZ * 512;    // B*512
    float* vm   = km + (long)B_SZ * 512;    // B*512
    float* o    = vm + (long)B_SZ * 512;    // B*512

    // k1 = inp @ Wk_i[1]   (4096x512x64)
    gemm_f32<<<dim3(1, 64, 1), 256, 0, stream>>>(
        inp, Wk_i + (long)NINP * 64, k1, NINP, NINP, 64, 64, 0, 0, 0);
    // q[b,kb,:] = hx_block @ Wq_i[kb]   (4096x256x64 per kb)
    gemm_f32<<<dim3(1, 64, 8), 256, 0, stream>>>(
        hx, Wq_i, q, BSZ, NHID, 64, 512, 256, (long)BSZ * 64, 64);
    // v1 = inp @ Wv_i[1]   (4096x512x1024)
    gemm_f32<<<dim3(16, 64, 1), 256, 0, stream>>>(
        inp, Wv_i + (long)NINP * ATT_OUT, v1, NINP, NINP, ATT_OUT, ATT_OUT, 0, 0, 0);
    // s1, w, mblk, mask
    s1_mask_kernel<<<dim3(B_SZ / 4), 256, 0, stream>>>(q, k1, w_ws, mblk, mask_out);
    // gates + LSTM -> h_new, c_new  (into d_out slots)
    gates_lstm_kernel<<<dim3(B_SZ / 32, 4, 8), 256, 0, stream>>>(
        v1, hx, cx, Wih, Whh, b_ih, b_hh, w_ws, h_out, c_out);
    // qm/km/vm = h_new_block @ W*_m[kb]
    gemm_f32<<<dim3(1, 64, 8), 256, 0, stream>>>(
        h_out, Wq_m, qm, BSZ, NHID, 64, 512, 256, (long)BSZ * 64, 64);
    gemm_f32<<<dim3(1, 64, 8), 256, 0, stream>>>(
        h_out, Wk_m, km, BSZ, NHID, 64, 512, 256, (long)BSZ * 64, 64);
    gemm_f32<<<dim3(1, 64, 8), 256, 0, stream>>>(
        h_out, Wv_m, vm, BSZ, NHID, 64, 512, 256, (long)BSZ * 64, 64);
    // inner attention -> o
    attn_m_kernel<<<dim3(B_SZ * 32 / 256), 256, 0, stream>>>(qm, km, vm, o);
    // epilogue: att_out, h_final, masked blend
    final_kernel<<<dim3(B_SZ * 8 / 8), 256, 0, stream>>>(
        o, gate_w, gate_b, fc_w, fc_b, mblk, hx, cx, h_out, c_out);
}

// Round 2
// 930.941 us; speedup vs baseline: 3.9006x; 3.9006x over previous
//
#include <hip/hip_runtime.h>
#include <hip/hip_bf16.h>

// BlocksCore forward. Round 2: gates GEMM -> bf16 MFMA (16x16x32), rest f32.
// B=4096, NINP=512, NHID=2048, NB=8, BS=256, ATT_OUT=1024, TOPK=4, DK_I=64, NH=4, DK_M=16

#define B_SZ 4096
#define NINP 512
#define NHID 2048
#define NB 8
#define BSZ 256
#define ATT_OUT 1024

typedef __attribute__((ext_vector_type(8))) short bf16x8;
typedef __attribute__((ext_vector_type(8))) unsigned short u16x8;
typedef __attribute__((ext_vector_type(4))) float f32x4;

__device__ __forceinline__ float sigf(float x) { return 1.0f / (1.0f + expf(-x)); }

__device__ __forceinline__ unsigned short f2bf(float x) {
    unsigned u = __float_as_uint(x);
    unsigned r = (u + 0x7fff + ((u >> 16) & 1)) >> 16;
    return (unsigned short)r;
}

// async global->LDS, 16B per lane. LDS dest must be wave-uniform base + lane*16.
__device__ __forceinline__ void gload16(const void* g, void* l) {
    __builtin_amdgcn_global_load_lds(
        (const __attribute__((address_space(1))) unsigned int*)(unsigned long long)g,
        (__attribute__((address_space(3))) unsigned int*)(unsigned int)(unsigned long long)l,
        16, 0, 0);
}

// ---------------------------------------------------------------------------
// f32 -> bf16 elementwise convert (8 elems/thread)
// ---------------------------------------------------------------------------
__global__ __launch_bounds__(256) void f2bf_kernel(
    const float4* __restrict__ in, u16x8* __restrict__ out, long n8)
{
    long i = (long)blockIdx.x * 256 + threadIdx.x;
    if (i >= n8) return;
    float4 a = in[i * 2], b = in[i * 2 + 1];
    u16x8 v;
    v[0] = f2bf(a.x); v[1] = f2bf(a.y); v[2] = f2bf(a.z); v[3] = f2bf(a.w);
    v[4] = f2bf(b.x); v[5] = f2bf(b.y); v[6] = f2bf(b.z); v[7] = f2bf(b.w);
    out[i] = v;
}

// ---------------------------------------------------------------------------
// Generic tiled f32 GEMM (as round 1). C[m,n] = sum_k A[m,k]*B[k,n].
// ---------------------------------------------------------------------------
__global__ __launch_bounds__(256) void gemm_f32(
    const float* __restrict__ A, const float* __restrict__ B, float* __restrict__ C,
    int K, int lda, int ldb, int ldc,
    long aOffZ, long bOffZ, long cOffZ)
{
    const int z = blockIdx.z;
    A += (long)z * aOffZ;
    B += (long)z * bOffZ;
    C += (long)z * cOffZ;
    const int n0 = blockIdx.x * 64;
    const int m0 = blockIdx.y * 64;

    __shared__ float As[64][17];
    __shared__ float Bs[16][65];

    const int t = threadIdx.x;
    const int ty = t >> 4;
    const int tx = t & 15;

    float acc[4][4] = {};

    for (int k0 = 0; k0 < K; k0 += 16) {
        {
            int m = t >> 2, kk = (t & 3) << 2;
            float4 av = *reinterpret_cast<const float4*>(&A[(long)(m0 + m) * lda + k0 + kk]);
            As[m][kk] = av.x; As[m][kk + 1] = av.y; As[m][kk + 2] = av.z; As[m][kk + 3] = av.w;
        }
        {
            int kr = t >> 4, c = (t & 15) << 2;
            float4 bv = *reinterpret_cast<const float4*>(&B[(long)(k0 + kr) * ldb + n0 + c]);
            Bs[kr][c] = bv.x; Bs[kr][c + 1] = bv.y; Bs[kr][c + 2] = bv.z; Bs[kr][c + 3] = bv.w;
        }
        __syncthreads();
        #pragma unroll
        for (int kk = 0; kk < 16; ++kk) {
            float a[4], b[4];
            #pragma unroll
            for (int i = 0; i < 4; ++i) a[i] = As[ty * 4 + i][kk];
            #pragma unroll
            for (int j = 0; j < 4; ++j) b[j] = Bs[kk][tx * 4 + j];
            #pragma unroll
            for (int i = 0; i < 4; ++i)
                #pragma unroll
                for (int j = 0; j < 4; ++j) acc[i][j] += a[i] * b[j];
        }
        __syncthreads();
    }
    #pragma unroll
    for (int i = 0; i < 4; ++i)
        #pragma unroll
        for (int j = 0; j < 4; ++j)
            C[(long)(m0 + ty * 4 + i) * ldc + n0 + tx * 4 + j] = acc[i][j];
}

// Same GEMM but stores bf16 output (for v1).
__global__ __launch_bounds__(256) void gemm_f32_bf16out(
    const float* __restrict__ A, const float* __restrict__ B, unsigned short* __restrict__ C,
    int K, int lda, int ldb, int ldc)
{
    const int n0 = blockIdx.x * 64;
    const int m0 = blockIdx.y * 64;

    __shared__ float As[64][17];
    __shared__ float Bs[16][65];

    const int t = threadIdx.x;
    const int ty = t >> 4;
    const int tx = t & 15;

    float acc[4][4] = {};

    for (int k0 = 0; k0 < K; k0 += 16) {
        {
            int m = t >> 2, kk = (t & 3) << 2;
            float4 av = *reinterpret_cast<const float4*>(&A[(long)(m0 + m) * lda + k0 + kk]);
            As[m][kk] = av.x; As[m][kk + 1] = av.y; As[m][kk + 2] = av.z; As[m][kk + 3] = av.w;
        }
        {
            int kr = t >> 4, c = (t & 15) << 2;
            float4 bv = *reinterpret_cast<const float4*>(&B[(long)(k0 + kr) * ldb + n0 + c]);
            Bs[kr][c] = bv.x; Bs[kr][c + 1] = bv.y; Bs[kr][c + 2] = bv.z; Bs[kr][c + 3] = bv.w;
        }
        __syncthreads();
        #pragma unroll
        for (int kk = 0; kk < 16; ++kk) {
            float a[4], b[4];
            #pragma unroll
            for (int i = 0; i < 4; ++i) a[i] = As[ty * 4 + i][kk];
            #pragma unroll
            for (int j = 0; j < 4; ++j) b[j] = Bs[kk][tx * 4 + j];
            #pragma unroll
            for (int i = 0; i < 4; ++i)
                #pragma unroll
                for (int j = 0; j < 4; ++j) acc[i][j] += a[i] * b[j];
        }
        __syncthreads();
    }
    #pragma unroll
    for (int i = 0; i < 4; ++i)
        #pragma unroll
        for (int j = 0; j < 4; ++j)
            C[(long)(m0 + ty * 4 + i) * ldc + n0 + tx * 4 + j] = f2bf(acc[i][j]);
}

// ---------------------------------------------------------------------------
// s1 / sigmoid weight / exact top-k mask (unchanged from round 1).
// ---------------------------------------------------------------------------
__global__ __launch_bounds__(256) void s1_mask_kernel(
    const float* __restrict__ q, const float* __restrict__ k1,
    float* __restrict__ w_ws, float* __restrict__ mblk,
    float* __restrict__ mask_out)
{
    const int wave = threadIdx.x >> 6;
    const int lane = threadIdx.x & 63;
    const int b = blockIdx.x * 4 + wave;

    float p[8];
    const float kv = k1[(long)b * 64 + lane];
    #pragma unroll
    for (int kb = 0; kb < 8; ++kb)
        p[kb] = q[(long)b * 512 + kb * 64 + lane] * kv;

    #pragma unroll
    for (int off = 1; off < 64; off <<= 1) {
        #pragma unroll
        for (int kb = 0; kb < 8; ++kb) p[kb] += __shfl_xor(p[kb], off);
    }

    float s[8], mv[8];
    #pragma unroll
    for (int kb = 0; kb < 8; ++kb) s[kb] = p[kb] * 0.125f;

    #pragma unroll
    for (int j = 0; j < 8; ++j) {
        int r = 0;
        #pragma unroll
        for (int i = 0; i < 8; ++i)
            r += (s[i] < s[j]) || (s[i] == s[j] && i < j);
        mv[j] = (r >= 4) ? 1.0f : 0.0f;
    }
    if (lane < 8) {
        w_ws[(long)b * 8 + lane] = sigf(s[lane]);
        mblk[(long)b * 8 + lane] = mv[lane];
    }
    #pragma unroll
    for (int it = 0; it < 32; ++it) {
        int idx = it * 64 + lane;
        mask_out[(long)b * 2048 + idx] = mv[idx >> 8];
    }
}

// ---------------------------------------------------------------------------
// MFMA gates + LSTM.
// Per kb: gates[b, sg*256+j] = w[b,kb]*(v1[b,:] . Wih[kb,sg*256+j,:])
//                             + hx[b,kb*256:+256] . Whh[kb,sg*256+j,:]
// Tile: 128 rows x 64 j x 4 segs. 4 waves: 2(M) x 2(J). BK=64.
// LDS linear dest for global_load_lds, XOR-8 16B-chunk swizzle applied via
// pre-swizzled global source + swizzled ds_read (both-sides rule).
// ---------------------------------------------------------------------------
__global__ __launch_bounds__(256, 2) void gates_mfma_kernel(
    const unsigned short* __restrict__ Ab,   // v1b  [4096][1024]
    const unsigned short* __restrict__ Hb,   // hxb  [4096][2048]
    const unsigned short* __restrict__ Wihb, // [8][1024][1024]  (row n, k)
    const unsigned short* __restrict__ Whhb, // [8][1024][256]
    const float* __restrict__ b_ih, const float* __restrict__ b_hh,
    const float* __restrict__ w_ws, const float* __restrict__ cx,
    float* __restrict__ h_out, float* __restrict__ c_out)
{
    const int m0 = blockIdx.x * 128;
    const int j0 = blockIdx.y * 64;
    const int kb = blockIdx.z;

    __shared__ unsigned short As[128 * 64];  // [r][8 chunks of 8 bf16], swizzled
    __shared__ unsigned short Bs[256 * 64];
    __shared__ float wv[128];

    const int t = threadIdx.x;
    const int wid = t >> 6;
    const int l = t & 63;
    const int l15 = l & 15;
    const int l4 = l >> 4;       // 0..3
    const int wm = wid >> 1;     // 0..1 (row half)
    const int wj = wid & 1;      // 0..1 (j half)

    if (t < 128) wv[t] = w_ws[(long)(m0 + t) * 8 + kb];

    f32x4 acc[4][8];
    #pragma unroll
    for (int m = 0; m < 4; ++m)
        #pragma unroll
        for (int n = 0; n < 8; ++n)
            acc[m][n] = (f32x4){0.f, 0.f, 0.f, 0.f};

    auto stage = [&](const unsigned short* Aptr, long lda,
                     const unsigned short* Bptr, long ldb, int k0) {
        #pragma unroll
        for (int s = 0; s < 4; ++s) {               // A: 1024 chunks, 16 segs
            int ci = (wid * 4 + s) * 64 + l;
            int r = ci >> 3, cs = ci & 7;
            const unsigned short* g = Aptr + (long)r * lda + k0 + ((cs ^ (r & 7)) << 3);
            gload16(g, &As[ci * 8]);
        }
        #pragma unroll
        for (int s = 0; s < 8; ++s) {               // B: 2048 chunks, 32 segs
            int ci = (wid * 8 + s) * 64 + l;
            int rn = ci >> 3, cs = ci & 7;
            int sg = rn >> 6, jl = rn & 63;
            const unsigned short* g = Bptr + (long)(sg * 256 + j0 + jl) * ldb + k0
                                      + ((cs ^ (rn & 7)) << 3);
            gload16(g, &Bs[ci * 8]);
        }
    };

    auto compute = [&]() {
        #pragma unroll
        for (int kh = 0; kh < 2; ++kh) {
            bf16x8 af[4];
            #pragma unroll
            for (int m = 0; m < 4; ++m) {
                int r = wm * 64 + m * 16 + l15;
                int c = kh * 4 + l4;
                af[m] = *reinterpret_cast<const bf16x8*>(&As[r * 64 + ((c ^ (r & 7)) << 3)]);
            }
            #pragma unroll
            for (int sg = 0; sg < 4; ++sg) {
                #pragma unroll
                for (int jf = 0; jf < 2; ++jf) {
                    int rn = sg * 64 + wj * 32 + jf * 16 + l15;
                    int c = kh * 4 + l4;
                    bf16x8 bf = *reinterpret_cast<const bf16x8*>(
                        &Bs[rn * 64 + ((c ^ (rn & 7)) << 3)]);
                    #pragma unroll
                    for (int m = 0; m < 4; ++m)
                        acc[m][sg * 2 + jf] = __builtin_amdgcn_mfma_f32_16x16x32_bf16(
                            af[m], bf, acc[m][sg * 2 + jf], 0, 0, 0);
                }
            }
        }
    };

    // ---- phase 1: K=1024 over v1b @ Wih^T ----
    {
        const unsigned short* A1 = Ab + (long)m0 * 1024;
        const unsigned short* B1 = Wihb + (long)kb * 1024 * 1024;
        for (int k0 = 0; k0 < 1024; k0 += 64) {
            stage(A1, 1024, B1, 1024, k0);
            __syncthreads();
            compute();
            __syncthreads();
        }
    }

    // ---- scale phase-1 result by w (per row) ----
    {
        float wsc[4][4];
        #pragma unroll
        for (int m = 0; m < 4; ++m)
            #pragma unroll
            for (int r = 0; r < 4; ++r)
                wsc[m][r] = wv[wm * 64 + m * 16 + l4 * 4 + r];
        #pragma unroll
        for (int m = 0; m < 4; ++m)
            #pragma unroll
            for (int n = 0; n < 8; ++n)
                #pragma unroll
                for (int r = 0; r < 4; ++r)
                    acc[m][n][r] *= wsc[m][r];
    }

    // ---- phase 2: K=256 over hx_block @ Whh^T ----
    {
        const unsigned short* A2 = Hb + (long)m0 * 2048 + kb * 256;
        const unsigned short* B2 = Whhb + (long)kb * 1024 * 256;
        for (int k0 = 0; k0 < 256; k0 += 64) {
            stage(A2, 2048, B2, 256, k0);
            __syncthreads();
            compute();
            __syncthreads();
        }
    }

    // ---- bias + LSTM epilogue, all 4 segments in-lane ----
    #pragma unroll
    for (int jf = 0; jf < 2; ++jf) {
        const int jcol = j0 + wj * 32 + jf * 16 + l15;
        const long bb = (long)kb * 1024 + jcol;
        const float bI = b_ih[bb] + b_hh[bb];
        const float bF = b_ih[bb + 256] + b_hh[bb + 256];
        const float bG = b_ih[bb + 512] + b_hh[bb + 512];
        const float bO = b_ih[bb + 768] + b_hh[bb + 768];
        #pragma unroll
        for (int m = 0; m < 4; ++m) {
            #pragma unroll
            for (int r = 0; r < 4; ++r) {
                const long row = m0 + wm * 64 + m * 16 + l4 * 4 + r;
                const long idx = row * 2048 + kb * 256 + jcol;
                const float ig = acc[m][0 + jf][r] + bI;
                const float fg = acc[m][2 + jf][r] + bF;
                const float gg = acc[m][4 + jf][r] + bG;
                const float og = acc[m][6 + jf][r] + bO;
                const float co = cx[idx];
                const float cn = sigf(fg) * co + sigf(ig) * tanhf(gg);
                const float hn = sigf(og) * tanhf(cn);
                h_out[idx] = hn;
                c_out[idx] = cn;
            }
        }
    }
}

// ---------------------------------------------------------------------------
// Inner NBxNB attention (unchanged).
// ---------------------------------------------------------------------------
__global__ __launch_bounds__(256) void attn_m_kernel(
    const float* __restrict__ qm, const float* __restrict__ km,
    const float* __restrict__ vm, float* __restrict__ o)
{
    const int tid = blockIdx.x * 256 + threadIdx.x;
    const int b = tid >> 5;
    const int qkb = (tid >> 2) & 7;
    const int h = tid & 3;

    const float* qp = qm + (long)b * 512 + qkb * 64 + h * 16;
    float qv[16];
    #pragma unroll
    for (int e = 0; e < 16; ++e) qv[e] = qp[e];

    float sc[8];
    float mx = -1e30f;
    #pragma unroll
    for (int kk = 0; kk < 8; ++kk) {
        const float* kp = km + (long)b * 512 + kk * 64 + h * 16;
        float s = 0.f;
        #pragma unroll
        for (int e = 0; e < 16; ++e) s += qv[e] * kp[e];
        s *= 0.25f;
        sc[kk] = s;
        mx = fmaxf(mx, s);
    }
    float den = 0.f;
    #pragma unroll
    for (int kk = 0; kk < 8; ++kk) { sc[kk] = expf(sc[kk] - mx); den += sc[kk]; }
    const float inv = 1.0f / den;

    float ov[16] = {};
    #pragma unroll
    for (int kk = 0; kk < 8; ++kk) {
        const float pw = sc[kk] * inv;
        const float* vp = vm + (long)b * 512 + kk * 64 + h * 16;
        #pragma unroll
        for (int e = 0; e < 16; ++e) ov[e] += pw * vp[e];
    }
    float* op = o + (long)b * 512 + qkb * 64 + h * 16;
    #pragma unroll
    for (int e = 0; e < 16; ++e) op[e] = ov[e];
}

// ---------------------------------------------------------------------------
// Epilogue: att_out, h_final, masked blend (unchanged).
// ---------------------------------------------------------------------------
__global__ __launch_bounds__(256) void final_kernel(
    const float* __restrict__ o,
    const float* __restrict__ gate_w, const float* __restrict__ gate_b,
    const float* __restrict__ fc_w, const float* __restrict__ fc_b,
    const float* __restrict__ mblk,
    const float* __restrict__ hx, const float* __restrict__ cx,
    float* __restrict__ h_out, float* __restrict__ c_out)
{
    __shared__ float osh[64];
    const int j = threadIdx.x;
    for (int it = 0; it < 8; ++it) {
        const int p = blockIdx.x * 8 + it;
        const int b = p >> 3;
        const int kb = p & 7;
        __syncthreads();
        if (j < 64) osh[j] = o[(long)b * 512 + kb * 64 + j];
        __syncthreads();

        float g1 = gate_b[j];
        float g2 = fc_b[j];
        #pragma unroll 8
        for (int e = 0; e < 64; ++e) {
            const float ov = osh[e];
            g1 += ov * gate_w[j * 64 + e];
            g2 += ov * fc_w[j * 64 + e];
        }
        const float att = sigf(g1) * tanhf(g2);
        const long idx = (long)b * 2048 + kb * 256 + j;
        const float m = mblk[(long)b * 8 + kb];
        const float hn = h_out[idx] + att;
        h_out[idx] = (m != 0.0f) ? hn : hx[idx];
        c_out[idx] = (m != 0.0f) ? c_out[idx] : cx[idx];
    }
}

// ---------------------------------------------------------------------------
extern "C" void kernel_launch(void* const* d_in, const int* in_sizes, int n_in,
                              void* d_out, int out_size, void* d_ws, size_t ws_size,
                              hipStream_t stream) {
    const float* inp    = (const float*)d_in[0];
    const float* hx     = (const float*)d_in[1];
    const float* cx     = (const float*)d_in[2];
    const float* Wq_i   = (const float*)d_in[3];
    const float* Wk_i   = (const float*)d_in[4];
    const float* Wv_i   = (const float*)d_in[5];
    const float* Wq_m   = (const float*)d_in[6];
    const float* Wk_m   = (const float*)d_in[7];
    const float* Wv_m   = (const float*)d_in[8];
    const float* fc_w   = (const float*)d_in[9];
    const float* fc_b   = (const float*)d_in[10];
    const float* gate_w = (const float*)d_in[11];
    const float* gate_b = (const float*)d_in[12];
    const float* Wih    = (const float*)d_in[13];
    const float* Whh    = (const float*)d_in[14];
    const float* b_ih   = (const float*)d_in[15];
    const float* b_hh   = (const float*)d_in[16];

    float* out      = (float*)d_out;
    float* h_out    = out;
    float* c_out    = out + (long)B_SZ * 2048;
    float* mask_out = out + (long)2 * B_SZ * 2048;

    // ---- workspace layout with lifetime aliasing (56.3 MiB total) ----
    float* ws   = (float*)d_ws;
    float* w_ws = ws;                                   // B*8
    float* mblk = w_ws + (long)B_SZ * 8;                // B*8
    unsigned short* v1b = (unsigned short*)(mblk + (long)B_SZ * 8);   // B*1024 bf16
    unsigned short* hxb = v1b + (long)B_SZ * 1024;                    // B*2048 bf16
    char* R = (char*)(hxb + (long)B_SZ * 2048);         // 33.6 MB aliased region
    // early (until s1_mask):
    float* k1 = (float*)R;                              // B*64
    float* q  = (float*)(R + (long)B_SZ * 64 * 4);      // B*512
    // mid (until gates):
    unsigned short* Wihb = (unsigned short*)R;          // 8*1024*1024 bf16
    unsigned short* Whhb = Wihb + (long)8 * 1024 * 1024;// 8*1024*256 bf16
    // late (after gates):
    float* qm = (float*)R;                              // B*512
    float* km = qm + (long)B_SZ * 512;
    float* vm = km + (long)B_SZ * 512;
    float* o  = vm + (long)B_SZ * 512;

    // hx -> bf16
    f2bf_kernel<<<dim3((B_SZ * 2048 / 8 + 255) / 256), 256, 0, stream>>>(
        (const float4*)hx, (u16x8*)hxb, (long)B_SZ * 2048 / 8);
    // k1 = inp @ Wk_i[1]
    gemm_f32<<<dim3(1, 64, 1), 256, 0, stream>>>(
        inp, Wk_i + (long)NINP * 64, k1, NINP, NINP, 64, 64, 0, 0, 0);
    // q[b,kb,:] = hx_block @ Wq_i[kb]
    gemm_f32<<<dim3(1, 64, 8), 256, 0, stream>>>(
        hx, Wq_i, q, BSZ, NHID, 64, 512, 256, (long)BSZ * 64, 64);
    // v1 = inp @ Wv_i[1]  -> bf16
    gemm_f32_bf16out<<<dim3(16, 64, 1), 256, 0, stream>>>(
        inp, Wv_i + (long)NINP * ATT_OUT, v1b, NINP, NINP, ATT_OUT, ATT_OUT);
    // s1, w, mblk, mask (consumes q,k1 -> R free after this)
    s1_mask_kernel<<<dim3(B_SZ / 4), 256, 0, stream>>>(q, k1, w_ws, mblk, mask_out);
    // weights -> bf16 (into R)
    f2bf_kernel<<<dim3((8 * 1024 * 1024 / 8 + 255) / 256), 256, 0, stream>>>(
        (const float4*)Wih, (u16x8*)Wihb, (long)8 * 1024 * 1024 / 8);
    f2bf_kernel<<<dim3((8 * 1024 * 256 / 8 + 255) / 256), 256, 0, stream>>>(
        (const float4*)Whh, (u16x8*)Whhb, (long)8 * 1024 * 256 / 8);
    // gates + LSTM (MFMA) -> h_new, c_new into d_out slots
    gates_mfma_kernel<<<dim3(B_SZ / 128, 4, 8), 256, 0, stream>>>(
        v1b, hxb, Wihb, Whhb, b_ih, b_hh, w_ws, cx, h_out, c_out);
    // qm/km/vm = h_new_block @ W*_m[kb]  (into R, after gates)
    gemm_f32<<<dim3(1, 64, 8), 256, 0, stream>>>(
        h_out, Wq_m, qm, BSZ, NHID, 64, 512, 256, (long)BSZ * 64, 64);
    gemm_f32<<<dim3(1, 64, 8), 256, 0, stream>>>(
        h_out, Wk_m, km, BSZ, NHID, 64, 512, 256, (long)BSZ * 64, 64);
    gemm_f32<<<dim3(1, 64, 8), 256, 0, stream>>>(
        h_out, Wv_m, vm, BSZ, NHID, 64, 512, 256, (long)BSZ * 64, 64);
    // inner attention -> o
    attn_m_kernel<<<dim3(B_SZ * 32 / 256), 256, 0, stream>>>(qm, km, vm, o);
    // epilogue
    final_kernel<<<dim3(B_SZ), 256, 0, stream>>>(
        o, gate_w, gate_b, fc_w, fc_b, mblk, hx, cx, h_out, c_out);
}

// Round 3
// 445.809 us; speedup vs baseline: 8.1453x; 2.0882x over previous
//
#include <hip/hip_runtime.h>
#include <hip/hip_bf16.h>

// BlocksCore forward. Round 3: fix final_kernel (uncoalesced weight gather ->
// transposed weights + wave-per-row register accumulation). Gates stays MFMA.

#define B_SZ 4096
#define NINP 512
#define NHID 2048
#define NB 8
#define BSZ 256
#define ATT_OUT 1024

typedef __attribute__((ext_vector_type(8))) short bf16x8;
typedef __attribute__((ext_vector_type(8))) unsigned short u16x8;
typedef __attribute__((ext_vector_type(4))) float f32x4;

__device__ __forceinline__ float sigf(float x) { return 1.0f / (1.0f + expf(-x)); }

__device__ __forceinline__ unsigned short f2bf(float x) {
    unsigned u = __float_as_uint(x);
    unsigned r = (u + 0x7fff + ((u >> 16) & 1)) >> 16;
    return (unsigned short)r;
}

// async global->LDS, 16B per lane. LDS dest must be wave-uniform base + lane*16.
__device__ __forceinline__ void gload16(const void* g, void* l) {
    __builtin_amdgcn_global_load_lds(
        (const __attribute__((address_space(1))) unsigned int*)(unsigned long long)g,
        (__attribute__((address_space(3))) unsigned int*)(unsigned int)(unsigned long long)l,
        16, 0, 0);
}

// ---------------------------------------------------------------------------
// f32 -> bf16 elementwise convert (8 elems/thread)
// ---------------------------------------------------------------------------
__global__ __launch_bounds__(256) void f2bf_kernel(
    const float4* __restrict__ in, u16x8* __restrict__ out, long n8)
{
    long i = (long)blockIdx.x * 256 + threadIdx.x;
    if (i >= n8) return;
    float4 a = in[i * 2], b = in[i * 2 + 1];
    u16x8 v;
    v[0] = f2bf(a.x); v[1] = f2bf(a.y); v[2] = f2bf(a.z); v[3] = f2bf(a.w);
    v[4] = f2bf(b.x); v[5] = f2bf(b.y); v[6] = f2bf(b.z); v[7] = f2bf(b.w);
    out[i] = v;
}

// ---------------------------------------------------------------------------
// Transpose the two 256x64 epilogue weights into [64][256] layout.
// ---------------------------------------------------------------------------
__global__ __launch_bounds__(256) void wtrans_kernel(
    const float* __restrict__ gw, const float* __restrict__ fw,
    float* __restrict__ Wtg, float* __restrict__ Wtf)
{
    int t = blockIdx.x * 256 + threadIdx.x;   // 0..16383
    if (t >= 16384) return;
    int j = t >> 6;
    int e = t & 63;
    Wtg[e * 256 + j] = gw[t];
    Wtf[e * 256 + j] = fw[t];
}

// ---------------------------------------------------------------------------
// Generic tiled f32 GEMM. C[m,n] = sum_k A[m,k]*B[k,n].
// ---------------------------------------------------------------------------
__global__ __launch_bounds__(256) void gemm_f32(
    const float* __restrict__ A, const float* __restrict__ B, float* __restrict__ C,
    int K, int lda, int ldb, int ldc,
    long aOffZ, long bOffZ, long cOffZ)
{
    const int z = blockIdx.z;
    A += (long)z * aOffZ;
    B += (long)z * bOffZ;
    C += (long)z * cOffZ;
    const int n0 = blockIdx.x * 64;
    const int m0 = blockIdx.y * 64;

    __shared__ float As[64][17];
    __shared__ float Bs[16][65];

    const int t = threadIdx.x;
    const int ty = t >> 4;
    const int tx = t & 15;

    float acc[4][4] = {};

    for (int k0 = 0; k0 < K; k0 += 16) {
        {
            int m = t >> 2, kk = (t & 3) << 2;
            float4 av = *reinterpret_cast<const float4*>(&A[(long)(m0 + m) * lda + k0 + kk]);
            As[m][kk] = av.x; As[m][kk + 1] = av.y; As[m][kk + 2] = av.z; As[m][kk + 3] = av.w;
        }
        {
            int kr = t >> 4, c = (t & 15) << 2;
            float4 bv = *reinterpret_cast<const float4*>(&B[(long)(k0 + kr) * ldb + n0 + c]);
            Bs[kr][c] = bv.x; Bs[kr][c + 1] = bv.y; Bs[kr][c + 2] = bv.z; Bs[kr][c + 3] = bv.w;
        }
        __syncthreads();
        #pragma unroll
        for (int kk = 0; kk < 16; ++kk) {
            float a[4], b[4];
            #pragma unroll
            for (int i = 0; i < 4; ++i) a[i] = As[ty * 4 + i][kk];
            #pragma unroll
            for (int j = 0; j < 4; ++j) b[j] = Bs[kk][tx * 4 + j];
            #pragma unroll
            for (int i = 0; i < 4; ++i)
                #pragma unroll
                for (int j = 0; j < 4; ++j) acc[i][j] += a[i] * b[j];
        }
        __syncthreads();
    }
    #pragma unroll
    for (int i = 0; i < 4; ++i)
        #pragma unroll
        for (int j = 0; j < 4; ++j)
            C[(long)(m0 + ty * 4 + i) * ldc + n0 + tx * 4 + j] = acc[i][j];
}

// Same GEMM but stores bf16 output (for v1).
__global__ __launch_bounds__(256) void gemm_f32_bf16out(
    const float* __restrict__ A, const float* __restrict__ B, unsigned short* __restrict__ C,
    int K, int lda, int ldb, int ldc)
{
    const int n0 = blockIdx.x * 64;
    const int m0 = blockIdx.y * 64;

    __shared__ float As[64][17];
    __shared__ float Bs[16][65];

    const int t = threadIdx.x;
    const int ty = t >> 4;
    const int tx = t & 15;

    float acc[4][4] = {};

    for (int k0 = 0; k0 < K; k0 += 16) {
        {
            int m = t >> 2, kk = (t & 3) << 2;
            float4 av = *reinterpret_cast<const float4*>(&A[(long)(m0 + m) * lda + k0 + kk]);
            As[m][kk] = av.x; As[m][kk + 1] = av.y; As[m][kk + 2] = av.z; As[m][kk + 3] = av.w;
        }
        {
            int kr = t >> 4, c = (t & 15) << 2;
            float4 bv = *reinterpret_cast<const float4*>(&B[(long)(k0 + kr) * ldb + n0 + c]);
            Bs[kr][c] = bv.x; Bs[kr][c + 1] = bv.y; Bs[kr][c + 2] = bv.z; Bs[kr][c + 3] = bv.w;
        }
        __syncthreads();
        #pragma unroll
        for (int kk = 0; kk < 16; ++kk) {
            float a[4], b[4];
            #pragma unroll
            for (int i = 0; i < 4; ++i) a[i] = As[ty * 4 + i][kk];
            #pragma unroll
            for (int j = 0; j < 4; ++j) b[j] = Bs[kk][tx * 4 + j];
            #pragma unroll
            for (int i = 0; i < 4; ++i)
                #pragma unroll
                for (int j = 0; j < 4; ++j) acc[i][j] += a[i] * b[j];
        }
        __syncthreads();
    }
    #pragma unroll
    for (int i = 0; i < 4; ++i)
        #pragma unroll
        for (int j = 0; j < 4; ++j)
            C[(long)(m0 + ty * 4 + i) * ldc + n0 + tx * 4 + j] = f2bf(acc[i][j]);
}

// ---------------------------------------------------------------------------
// s1 / sigmoid weight / exact top-k mask.
// ---------------------------------------------------------------------------
__global__ __launch_bounds__(256) void s1_mask_kernel(
    const float* __restrict__ q, const float* __restrict__ k1,
    float* __restrict__ w_ws, float* __restrict__ mblk,
    float* __restrict__ mask_out)
{
    const int wave = threadIdx.x >> 6;
    const int lane = threadIdx.x & 63;
    const int b = blockIdx.x * 4 + wave;

    float p[8];
    const float kv = k1[(long)b * 64 + lane];
    #pragma unroll
    for (int kb = 0; kb < 8; ++kb)
        p[kb] = q[(long)b * 512 + kb * 64 + lane] * kv;

    #pragma unroll
    for (int off = 1; off < 64; off <<= 1) {
        #pragma unroll
        for (int kb = 0; kb < 8; ++kb) p[kb] += __shfl_xor(p[kb], off);
    }

    float s[8], mv[8];
    #pragma unroll
    for (int kb = 0; kb < 8; ++kb) s[kb] = p[kb] * 0.125f;

    #pragma unroll
    for (int j = 0; j < 8; ++j) {
        int r = 0;
        #pragma unroll
        for (int i = 0; i < 8; ++i)
            r += (s[i] < s[j]) || (s[i] == s[j] && i < j);
        mv[j] = (r >= 4) ? 1.0f : 0.0f;
    }
    if (lane < 8) {
        w_ws[(long)b * 8 + lane] = sigf(s[lane]);
        mblk[(long)b * 8 + lane] = mv[lane];
    }
    #pragma unroll
    for (int it = 0; it < 32; ++it) {
        int idx = it * 64 + lane;
        mask_out[(long)b * 2048 + idx] = mv[idx >> 8];
    }
}

// ---------------------------------------------------------------------------
// MFMA gates + LSTM (unchanged from round 2).
// ---------------------------------------------------------------------------
__global__ __launch_bounds__(256, 2) void gates_mfma_kernel(
    const unsigned short* __restrict__ Ab,   // v1b  [4096][1024]
    const unsigned short* __restrict__ Hb,   // hxb  [4096][2048]
    const unsigned short* __restrict__ Wihb, // [8][1024][1024]
    const unsigned short* __restrict__ Whhb, // [8][1024][256]
    const float* __restrict__ b_ih, const float* __restrict__ b_hh,
    const float* __restrict__ w_ws, const float* __restrict__ cx,
    float* __restrict__ h_out, float* __restrict__ c_out)
{
    const int m0 = blockIdx.x * 128;
    const int j0 = blockIdx.y * 64;
    const int kb = blockIdx.z;

    __shared__ unsigned short As[128 * 64];
    __shared__ unsigned short Bs[256 * 64];
    __shared__ float wv[128];

    const int t = threadIdx.x;
    const int wid = t >> 6;
    const int l = t & 63;
    const int l15 = l & 15;
    const int l4 = l >> 4;
    const int wm = wid >> 1;
    const int wj = wid & 1;

    if (t < 128) wv[t] = w_ws[(long)(m0 + t) * 8 + kb];

    f32x4 acc[4][8];
    #pragma unroll
    for (int m = 0; m < 4; ++m)
        #pragma unroll
        for (int n = 0; n < 8; ++n)
            acc[m][n] = (f32x4){0.f, 0.f, 0.f, 0.f};

    auto stage = [&](const unsigned short* Aptr, long lda,
                     const unsigned short* Bptr, long ldb, int k0) {
        #pragma unroll
        for (int s = 0; s < 4; ++s) {
            int ci = (wid * 4 + s) * 64 + l;
            int r = ci >> 3, cs = ci & 7;
            const unsigned short* g = Aptr + (long)r * lda + k0 + ((cs ^ (r & 7)) << 3);
            gload16(g, &As[ci * 8]);
        }
        #pragma unroll
        for (int s = 0; s < 8; ++s) {
            int ci = (wid * 8 + s) * 64 + l;
            int rn = ci >> 3, cs = ci & 7;
            int sg = rn >> 6, jl = rn & 63;
            const unsigned short* g = Bptr + (long)(sg * 256 + j0 + jl) * ldb + k0
                                      + ((cs ^ (rn & 7)) << 3);
            gload16(g, &Bs[ci * 8]);
        }
    };

    auto compute = [&]() {
        #pragma unroll
        for (int kh = 0; kh < 2; ++kh) {
            bf16x8 af[4];
            #pragma unroll
            for (int m = 0; m < 4; ++m) {
                int r = wm * 64 + m * 16 + l15;
                int c = kh * 4 + l4;
                af[m] = *reinterpret_cast<const bf16x8*>(&As[r * 64 + ((c ^ (r & 7)) << 3)]);
            }
            #pragma unroll
            for (int sg = 0; sg < 4; ++sg) {
                #pragma unroll
                for (int jf = 0; jf < 2; ++jf) {
                    int rn = sg * 64 + wj * 32 + jf * 16 + l15;
                    int c = kh * 4 + l4;
                    bf16x8 bf = *reinterpret_cast<const bf16x8*>(
                        &Bs[rn * 64 + ((c ^ (rn & 7)) << 3)]);
                    #pragma unroll
                    for (int m = 0; m < 4; ++m)
                        acc[m][sg * 2 + jf] = __builtin_amdgcn_mfma_f32_16x16x32_bf16(
                            af[m], bf, acc[m][sg * 2 + jf], 0, 0, 0);
                }
            }
        }
    };

    {
        const unsigned short* A1 = Ab + (long)m0 * 1024;
        const unsigned short* B1 = Wihb + (long)kb * 1024 * 1024;
        for (int k0 = 0; k0 < 1024; k0 += 64) {
            stage(A1, 1024, B1, 1024, k0);
            __syncthreads();
            compute();
            __syncthreads();
        }
    }

    {
        float wsc[4][4];
        #pragma unroll
        for (int m = 0; m < 4; ++m)
            #pragma unroll
            for (int r = 0; r < 4; ++r)
                wsc[m][r] = wv[wm * 64 + m * 16 + l4 * 4 + r];
        #pragma unroll
        for (int m = 0; m < 4; ++m)
            #pragma unroll
            for (int n = 0; n < 8; ++n)
                #pragma unroll
                for (int r = 0; r < 4; ++r)
                    acc[m][n][r] *= wsc[m][r];
    }

    {
        const unsigned short* A2 = Hb + (long)m0 * 2048 + kb * 256;
        const unsigned short* B2 = Whhb + (long)kb * 1024 * 256;
        for (int k0 = 0; k0 < 256; k0 += 64) {
            stage(A2, 2048, B2, 256, k0);
            __syncthreads();
            compute();
            __syncthreads();
        }
    }

    #pragma unroll
    for (int jf = 0; jf < 2; ++jf) {
        const int jcol = j0 + wj * 32 + jf * 16 + l15;
        const long bb = (long)kb * 1024 + jcol;
        const float bI = b_ih[bb] + b_hh[bb];
        const float bF = b_ih[bb + 256] + b_hh[bb + 256];
        const float bG = b_ih[bb + 512] + b_hh[bb + 512];
        const float bO = b_ih[bb + 768] + b_hh[bb + 768];
        #pragma unroll
        for (int m = 0; m < 4; ++m) {
            #pragma unroll
            for (int r = 0; r < 4; ++r) {
                const long row = m0 + wm * 64 + m * 16 + l4 * 4 + r;
                const long idx = row * 2048 + kb * 256 + jcol;
                const float ig = acc[m][0 + jf][r] + bI;
                const float fg = acc[m][2 + jf][r] + bF;
                const float gg = acc[m][4 + jf][r] + bG;
                const float og = acc[m][6 + jf][r] + bO;
                const float co = cx[idx];
                const float cn = sigf(fg) * co + sigf(ig) * tanhf(gg);
                const float hn = sigf(og) * tanhf(cn);
                h_out[idx] = hn;
                c_out[idx] = cn;
            }
        }
    }
}

// ---------------------------------------------------------------------------
// Inner NBxNB attention (unchanged).
// ---------------------------------------------------------------------------
__global__ __launch_bounds__(256) void attn_m_kernel(
    const float* __restrict__ qm, const float* __restrict__ km,
    const float* __restrict__ vm, float* __restrict__ o)
{
    const int tid = blockIdx.x * 256 + threadIdx.x;
    const int b = tid >> 5;
    const int qkb = (tid >> 2) & 7;
    const int h = tid & 3;

    const float* qp = qm + (long)b * 512 + qkb * 64 + h * 16;
    float qv[16];
    #pragma unroll
    for (int e = 0; e < 16; ++e) qv[e] = qp[e];

    float sc[8];
    float mx = -1e30f;
    #pragma unroll
    for (int kk = 0; kk < 8; ++kk) {
        const float* kp = km + (long)b * 512 + kk * 64 + h * 16;
        float s = 0.f;
        #pragma unroll
        for (int e = 0; e < 16; ++e) s += qv[e] * kp[e];
        s *= 0.25f;
        sc[kk] = s;
        mx = fmaxf(mx, s);
    }
    float den = 0.f;
    #pragma unroll
    for (int kk = 0; kk < 8; ++kk) { sc[kk] = expf(sc[kk] - mx); den += sc[kk]; }
    const float inv = 1.0f / den;

    float ov[16] = {};
    #pragma unroll
    for (int kk = 0; kk < 8; ++kk) {
        const float pw = sc[kk] * inv;
        const float* vp = vm + (long)b * 512 + kk * 64 + h * 16;
        #pragma unroll
        for (int e = 0; e < 16; ++e) ov[e] += pw * vp[e];
    }
    float* op = o + (long)b * 512 + qkb * 64 + h * 16;
    #pragma unroll
    for (int e = 0; e < 16; ++e) op[e] = ov[e];
}

// ---------------------------------------------------------------------------
// Epilogue v2: one wave per batch row b. Transposed weights (coalesced float4
// reads, streamed once per 8 pairs), o-row staged in LDS, f32 math identical
// to the reference path.
// ---------------------------------------------------------------------------
__global__ __launch_bounds__(256) void final_kernel2(
    const float* __restrict__ o,
    const float* __restrict__ Wtg, const float* __restrict__ Wtf,
    const float* __restrict__ gate_b, const float* __restrict__ fc_b,
    const float* __restrict__ mblk,
    const float* __restrict__ hx, const float* __restrict__ cx,
    float* __restrict__ h_out, float* __restrict__ c_out)
{
    __shared__ float osh[4][512];
    const int w = threadIdx.x >> 6;
    const int l = threadIdx.x & 63;
    const int b = blockIdx.x * 4 + w;
    const int j = l * 4;

    // stage this wave's o-row (512 f32) into LDS
    {
        const float4* op = (const float4*)(o + (long)b * 512);
        *(float4*)&osh[w][l * 8]     = op[l * 2];
        *(float4*)&osh[w][l * 8 + 4] = op[l * 2 + 1];
    }
    __builtin_amdgcn_s_waitcnt(0);  // wave-local: LDS written by own wave only

    float accg[8][4] = {};
    float accf[8][4] = {};

    #pragma unroll 4
    for (int e = 0; e < 64; ++e) {
        const float4 wg = *(const float4*)&Wtg[e * 256 + j];
        const float4 wf = *(const float4*)&Wtf[e * 256 + j];
        #pragma unroll
        for (int kb = 0; kb < 8; ++kb) {
            const float ov = osh[w][kb * 64 + e];
            accg[kb][0] += ov * wg.x; accg[kb][1] += ov * wg.y;
            accg[kb][2] += ov * wg.z; accg[kb][3] += ov * wg.w;
            accf[kb][0] += ov * wf.x; accf[kb][1] += ov * wf.y;
            accf[kb][2] += ov * wf.z; accf[kb][3] += ov * wf.w;
        }
    }

    const float4 gb = *(const float4*)&gate_b[j];
    const float4 fb = *(const float4*)&fc_b[j];

    #pragma unroll
    for (int kb = 0; kb < 8; ++kb) {
        const long idx = (long)b * 2048 + kb * 256 + j;
        const float m = mblk[(long)b * 8 + kb];
        float4 hn = *(const float4*)&h_out[idx];
        float4 cn = *(const float4*)&c_out[idx];
        const float4 hxv = *(const float4*)&hx[idx];
        const float4 cxv = *(const float4*)&cx[idx];
        float att0 = sigf(accg[kb][0] + gb.x) * tanhf(accf[kb][0] + fb.x);
        float att1 = sigf(accg[kb][1] + gb.y) * tanhf(accf[kb][1] + fb.y);
        float att2 = sigf(accg[kb][2] + gb.z) * tanhf(accf[kb][2] + fb.z);
        float att3 = sigf(accg[kb][3] + gb.w) * tanhf(accf[kb][3] + fb.w);
        hn.x += att0; hn.y += att1; hn.z += att2; hn.w += att3;
        if (m == 0.0f) { hn = hxv; cn = cxv; }
        *(float4*)&h_out[idx] = hn;
        *(float4*)&c_out[idx] = cn;
    }
}

// ---------------------------------------------------------------------------
extern "C" void kernel_launch(void* const* d_in, const int* in_sizes, int n_in,
                              void* d_out, int out_size, void* d_ws, size_t ws_size,
                              hipStream_t stream) {
    const float* inp    = (const float*)d_in[0];
    const float* hx     = (const float*)d_in[1];
    const float* cx     = (const float*)d_in[2];
    const float* Wq_i   = (const float*)d_in[3];
    const float* Wk_i   = (const float*)d_in[4];
    const float* Wv_i   = (const float*)d_in[5];
    const float* Wq_m   = (const float*)d_in[6];
    const float* Wk_m   = (const float*)d_in[7];
    const float* Wv_m   = (const float*)d_in[8];
    const float* fc_w   = (const float*)d_in[9];
    const float* fc_b   = (const float*)d_in[10];
    const float* gate_w = (const float*)d_in[11];
    const float* gate_b = (const float*)d_in[12];
    const float* Wih    = (const float*)d_in[13];
    const float* Whh    = (const float*)d_in[14];
    const float* b_ih   = (const float*)d_in[15];
    const float* b_hh   = (const float*)d_in[16];

    float* out      = (float*)d_out;
    float* h_out    = out;
    float* c_out    = out + (long)B_SZ * 2048;
    float* mask_out = out + (long)2 * B_SZ * 2048;

    // ---- workspace layout with lifetime aliasing ----
    float* ws   = (float*)d_ws;
    float* w_ws = ws;                                   // B*8
    float* mblk = w_ws + (long)B_SZ * 8;                // B*8
    unsigned short* v1b = (unsigned short*)(mblk + (long)B_SZ * 8);   // B*1024 bf16
    unsigned short* hxb = v1b + (long)B_SZ * 1024;                    // B*2048 bf16
    char* R = (char*)(hxb + (long)B_SZ * 2048);         // 33.6 MB aliased region
    // early (until s1_mask):
    float* k1 = (float*)R;                              // B*64
    float* q  = (float*)(R + (long)B_SZ * 64 * 4);      // B*512
    // mid (until gates):
    unsigned short* Wihb = (unsigned short*)R;          // 8*1024*1024 bf16
    unsigned short* Whhb = Wihb + (long)8 * 1024 * 1024;// 8*1024*256 bf16
    // late (after gates):
    float* qm = (float*)R;                              // B*512
    float* km = qm + (long)B_SZ * 512;
    float* vm = km + (long)B_SZ * 512;
    float* o  = vm + (long)B_SZ * 512;
    // persistent (beyond every aliased extent):
    float* Wt_g = o + (long)B_SZ * 512;                 // 64*256
    float* Wt_f = Wt_g + 64 * 256;                      // 64*256

    // transposed epilogue weights (conflict-free region, launch first)
    wtrans_kernel<<<dim3(64), 256, 0, stream>>>(gate_w, fc_w, Wt_g, Wt_f);
    // hx -> bf16
    f2bf_kernel<<<dim3((B_SZ * 2048 / 8 + 255) / 256), 256, 0, stream>>>(
        (const float4*)hx, (u16x8*)hxb, (long)B_SZ * 2048 / 8);
    // k1 = inp @ Wk_i[1]
    gemm_f32<<<dim3(1, 64, 1), 256, 0, stream>>>(
        inp, Wk_i + (long)NINP * 64, k1, NINP, NINP, 64, 64, 0, 0, 0);
    // q[b,kb,:] = hx_block @ Wq_i[kb]
    gemm_f32<<<dim3(1, 64, 8), 256, 0, stream>>>(
        hx, Wq_i, q, BSZ, NHID, 64, 512, 256, (long)BSZ * 64, 64);
    // v1 = inp @ Wv_i[1]  -> bf16
    gemm_f32_bf16out<<<dim3(16, 64, 1), 256, 0, stream>>>(
        inp, Wv_i + (long)NINP * ATT_OUT, v1b, NINP, NINP, ATT_OUT, ATT_OUT);
    // s1, w, mblk, mask (consumes q,k1 -> R free after this)
    s1_mask_kernel<<<dim3(B_SZ / 4), 256, 0, stream>>>(q, k1, w_ws, mblk, mask_out);
    // weights -> bf16 (into R)
    f2bf_kernel<<<dim3((8 * 1024 * 1024 / 8 + 255) / 256), 256, 0, stream>>>(
        (const float4*)Wih, (u16x8*)Wihb, (long)8 * 1024 * 1024 / 8);
    f2bf_kernel<<<dim3((8 * 1024 * 256 / 8 + 255) / 256), 256, 0, stream>>>(
        (const float4*)Whh, (u16x8*)Whhb, (long)8 * 1024 * 256 / 8);
    // gates + LSTM (MFMA) -> h_new, c_new into d_out slots
    gates_mfma_kernel<<<dim3(B_SZ / 128, 4, 8), 256, 0, stream>>>(
        v1b, hxb, Wihb, Whhb, b_ih, b_hh, w_ws, cx, h_out, c_out);
    // qm/km/vm = h_new_block @ W*_m[kb]  (into R, after gates)
    gemm_f32<<<dim3(1, 64, 8), 256, 0, stream>>>(
        h_out, Wq_m, qm, BSZ, NHID, 64, 512, 256, (long)BSZ * 64, 64);
    gemm_f32<<<dim3(1, 64, 8), 256, 0, stream>>>(
        h_out, Wk_m, km, BSZ, NHID, 64, 512, 256, (long)BSZ * 64, 64);
    gemm_f32<<<dim3(1, 64, 8), 256, 0, stream>>>(
        h_out, Wv_m, vm, BSZ, NHID, 64, 512, 256, (long)BSZ * 64, 64);
    // inner attention -> o
    attn_m_kernel<<<dim3(B_SZ * 32 / 256), 256, 0, stream>>>(qm, km, vm, o);
    // epilogue v2
    final_kernel2<<<dim3(B_SZ / 4), 256, 0, stream>>>(
        o, Wt_g, Wt_f, gate_b, fc_b, mblk, hx, cx, h_out, c_out);
}

// Round 4
// 322.589 us; speedup vs baseline: 11.2566x; 1.3820x over previous
//
#include <hip/hip_runtime.h>
#include <hip/hip_bf16.h>

// BlocksCore forward. Round 4: all large GEMMs on bf16 MFMA.
// Mask-critical q/k1/s1 path stays f32.

#define B_SZ 4096
#define NINP 512
#define NHID 2048
#define NB 8
#define BSZ 256
#define ATT_OUT 1024

typedef __attribute__((ext_vector_type(8))) short bf16x8;
typedef __attribute__((ext_vector_type(8))) unsigned short u16x8;
typedef __attribute__((ext_vector_type(4))) float f32x4;

__device__ __forceinline__ float sigf(float x) { return 1.0f / (1.0f + expf(-x)); }

__device__ __forceinline__ unsigned short f2bf(float x) {
    unsigned u = __float_as_uint(x);
    unsigned r = (u + 0x7fff + ((u >> 16) & 1)) >> 16;
    return (unsigned short)r;
}
__device__ __forceinline__ float bf2f(unsigned short u) {
    return __uint_as_float((unsigned)u << 16);
}

// async global->LDS, 16B per lane. LDS dest must be wave-uniform base + lane*16.
__device__ __forceinline__ void gload16(const void* g, void* l) {
    __builtin_amdgcn_global_load_lds(
        (const __attribute__((address_space(1))) unsigned int*)(unsigned long long)g,
        (__attribute__((address_space(3))) unsigned int*)(unsigned int)(unsigned long long)l,
        16, 0, 0);
}

// ---------------------------------------------------------------------------
// f32 -> bf16 elementwise convert (8 elems/thread)
// ---------------------------------------------------------------------------
__global__ __launch_bounds__(256) void f2bf_kernel(
    const float4* __restrict__ in, u16x8* __restrict__ out, long n8)
{
    long i = (long)blockIdx.x * 256 + threadIdx.x;
    if (i >= n8) return;
    float4 a = in[i * 2], b = in[i * 2 + 1];
    u16x8 v;
    v[0] = f2bf(a.x); v[1] = f2bf(a.y); v[2] = f2bf(a.z); v[3] = f2bf(a.w);
    v[4] = f2bf(b.x); v[5] = f2bf(b.y); v[6] = f2bf(b.z); v[7] = f2bf(b.w);
    out[i] = v;
}

// ---------------------------------------------------------------------------
// Transpose the two 256x64 epilogue weights into [64][256] layout.
// ---------------------------------------------------------------------------
__global__ __launch_bounds__(256) void wtrans_kernel(
    const float* __restrict__ gw, const float* __restrict__ fw,
    float* __restrict__ Wtg, float* __restrict__ Wtf)
{
    int t = blockIdx.x * 256 + threadIdx.x;   // 0..16383
    if (t >= 16384) return;
    int j = t >> 6;
    int e = t & 63;
    Wtg[e * 256 + j] = gw[t];
    Wtf[e * 256 + j] = fw[t];
}

// ---------------------------------------------------------------------------
// Wv_i[1] [512][1024] f32 -> Wvb [1024][512] bf16 (LDS tile transpose).
// grid (1024/32, 512/32), block 256 = 32(tx) x 8(ty).
// ---------------------------------------------------------------------------
__global__ __launch_bounds__(256) void wv_trans_kernel(
    const float* __restrict__ src, unsigned short* __restrict__ dst)
{
    __shared__ float tile[32][33];
    const int n0 = blockIdx.x * 32;
    const int k0 = blockIdx.y * 32;
    const int tx = threadIdx.x & 31;
    const int ty = threadIdx.x >> 5;
    #pragma unroll
    for (int r = 0; r < 4; ++r)
        tile[ty + r * 8][tx] = src[(long)(k0 + ty + r * 8) * 1024 + n0 + tx];
    __syncthreads();
    #pragma unroll
    for (int r = 0; r < 4; ++r)
        dst[(long)(n0 + ty + r * 8) * 512 + k0 + tx] = f2bf(tile[tx][ty + r * 8]);
}

// ---------------------------------------------------------------------------
// Wq_m/Wk_m/Wv_m [8][256][64] f32 -> Wqkvb [8][192][256] bf16 (n-major concat).
// ---------------------------------------------------------------------------
__global__ __launch_bounds__(256) void qkvw_kernel(
    const float* __restrict__ Wq, const float* __restrict__ Wk,
    const float* __restrict__ Wv, unsigned short* __restrict__ out)
{
    int idx = blockIdx.x * 256 + threadIdx.x;      // 0..393215
    int k = idx & 255;
    int n = (idx >> 8) % 192;
    int kb = idx / (192 * 256);
    const float* src = (n < 64) ? Wq : (n < 128) ? Wk : Wv;
    int nn = n & 63;
    out[idx] = f2bf(src[(long)kb * 16384 + k * 64 + nn]);
}

// ---------------------------------------------------------------------------
// Generic tiled f32 GEMM (kept for the mask-critical k1/q path).
// ---------------------------------------------------------------------------
__global__ __launch_bounds__(256) void gemm_f32(
    const float* __restrict__ A, const float* __restrict__ B, float* __restrict__ C,
    int K, int lda, int ldb, int ldc,
    long aOffZ, long bOffZ, long cOffZ)
{
    const int z = blockIdx.z;
    A += (long)z * aOffZ;
    B += (long)z * bOffZ;
    C += (long)z * cOffZ;
    const int n0 = blockIdx.x * 64;
    const int m0 = blockIdx.y * 64;

    __shared__ float As[64][17];
    __shared__ float Bs[16][65];

    const int t = threadIdx.x;
    const int ty = t >> 4;
    const int tx = t & 15;

    float acc[4][4] = {};

    for (int k0 = 0; k0 < K; k0 += 16) {
        {
            int m = t >> 2, kk = (t & 3) << 2;
            float4 av = *reinterpret_cast<const float4*>(&A[(long)(m0 + m) * lda + k0 + kk]);
            As[m][kk] = av.x; As[m][kk + 1] = av.y; As[m][kk + 2] = av.z; As[m][kk + 3] = av.w;
        }
        {
            int kr = t >> 4, c = (t & 15) << 2;
            float4 bv = *reinterpret_cast<const float4*>(&B[(long)(k0 + kr) * ldb + n0 + c]);
            Bs[kr][c] = bv.x; Bs[kr][c + 1] = bv.y; Bs[kr][c + 2] = bv.z; Bs[kr][c + 3] = bv.w;
        }
        __syncthreads();
        #pragma unroll
        for (int kk = 0; kk < 16; ++kk) {
            float a[4], b[4];
            #pragma unroll
            for (int i = 0; i < 4; ++i) a[i] = As[ty * 4 + i][kk];
            #pragma unroll
            for (int j = 0; j < 4; ++j) b[j] = Bs[kk][tx * 4 + j];
            #pragma unroll
            for (int i = 0; i < 4; ++i)
                #pragma unroll
                for (int j = 0; j < 4; ++j) acc[i][j] += a[i] * b[j];
        }
        __syncthreads();
    }
    #pragma unroll
    for (int i = 0; i < 4; ++i)
        #pragma unroll
        for (int j = 0; j < 4; ++j)
            C[(long)(m0 + ty * 4 + i) * ldc + n0 + tx * 4 + j] = acc[i][j];
}

// ---------------------------------------------------------------------------
// Generic bf16 MFMA GEMM: C[m,n] = sum_k A[m,k] * B[n,k]  (B is N x K).
// Tile 128(M) x 64(N), BK=64, 4 waves (2M x 2N), wave tile 64x32.
// Swizzled global_load_lds staging (both-sides XOR-8 chunk swizzle).
// OBF: 1 -> bf16 output, 0 -> f32 output.
// ---------------------------------------------------------------------------
template<int OBF>
__global__ __launch_bounds__(256, 2) void gemm_mfma(
    const unsigned short* __restrict__ A,
    const unsigned short* __restrict__ Bm,
    void* __restrict__ Cv,
    int K, int lda, int ldb, int ldc,
    long aOffZ, long bOffZ, long cOffZ)
{
    const int m0 = blockIdx.x * 128;
    const int n0 = blockIdx.y * 64;
    const int z = blockIdx.z;
    A += (long)z * aOffZ;
    Bm += (long)z * bOffZ;

    __shared__ unsigned short As[128 * 64];
    __shared__ unsigned short Bs[64 * 64];

    const int t = threadIdx.x;
    const int wid = t >> 6;
    const int l = t & 63;
    const int l15 = l & 15;
    const int l4 = l >> 4;
    const int wm = wid >> 1;
    const int wn = wid & 1;

    f32x4 acc[4][2];
    #pragma unroll
    for (int m = 0; m < 4; ++m)
        #pragma unroll
        for (int n = 0; n < 2; ++n)
            acc[m][n] = (f32x4){0.f, 0.f, 0.f, 0.f};

    for (int k0 = 0; k0 < K; k0 += 64) {
        #pragma unroll
        for (int s = 0; s < 4; ++s) {               // A: 1024 chunks
            int ci = (wid * 4 + s) * 64 + l;
            int r = ci >> 3, cs = ci & 7;
            const unsigned short* g = A + (long)(m0 + r) * lda + k0 + ((cs ^ (r & 7)) << 3);
            gload16(g, &As[ci * 8]);
        }
        #pragma unroll
        for (int s = 0; s < 2; ++s) {               // B: 512 chunks
            int ci = (wid * 2 + s) * 64 + l;
            int rn = ci >> 3, cs = ci & 7;
            const unsigned short* g = Bm + (long)(n0 + rn) * ldb + k0 + ((cs ^ (rn & 7)) << 3);
            gload16(g, &Bs[ci * 8]);
        }
        __syncthreads();
        #pragma unroll
        for (int kh = 0; kh < 2; ++kh) {
            bf16x8 af[4];
            #pragma unroll
            for (int m = 0; m < 4; ++m) {
                int r = wm * 64 + m * 16 + l15;
                int c = kh * 4 + l4;
                af[m] = *reinterpret_cast<const bf16x8*>(&As[r * 64 + ((c ^ (r & 7)) << 3)]);
            }
            #pragma unroll
            for (int nf = 0; nf < 2; ++nf) {
                int rn = wn * 32 + nf * 16 + l15;
                int c = kh * 4 + l4;
                bf16x8 bf = *reinterpret_cast<const bf16x8*>(
                    &Bs[rn * 64 + ((c ^ (rn & 7)) << 3)]);
                #pragma unroll
                for (int m = 0; m < 4; ++m)
                    acc[m][nf] = __builtin_amdgcn_mfma_f32_16x16x32_bf16(
                        af[m], bf, acc[m][nf], 0, 0, 0);
            }
        }
        __syncthreads();
    }

    #pragma unroll
    for (int nf = 0; nf < 2; ++nf) {
        const int ccol = n0 + wn * 32 + nf * 16 + l15;
        #pragma unroll
        for (int m = 0; m < 4; ++m) {
            #pragma unroll
            for (int r = 0; r < 4; ++r) {
                const long crow = m0 + wm * 64 + m * 16 + l4 * 4 + r;
                if (OBF)
                    ((unsigned short*)Cv)[(long)z * cOffZ + crow * ldc + ccol] =
                        f2bf(acc[m][nf][r]);
                else
                    ((float*)Cv)[(long)z * cOffZ + crow * ldc + ccol] = acc[m][nf][r];
            }
        }
    }
}

// ---------------------------------------------------------------------------
// s1 / sigmoid weight / exact top-k mask (f32, mask-critical).
// ---------------------------------------------------------------------------
__global__ __launch_bounds__(256) void s1_mask_kernel(
    const float* __restrict__ q, const float* __restrict__ k1,
    float* __restrict__ w_ws, float* __restrict__ mblk,
    float* __restrict__ mask_out)
{
    const int wave = threadIdx.x >> 6;
    const int lane = threadIdx.x & 63;
    const int b = blockIdx.x * 4 + wave;

    float p[8];
    const float kv = k1[(long)b * 64 + lane];
    #pragma unroll
    for (int kb = 0; kb < 8; ++kb)
        p[kb] = q[(long)b * 512 + kb * 64 + lane] * kv;

    #pragma unroll
    for (int off = 1; off < 64; off <<= 1) {
        #pragma unroll
        for (int kb = 0; kb < 8; ++kb) p[kb] += __shfl_xor(p[kb], off);
    }

    float s[8], mv[8];
    #pragma unroll
    for (int kb = 0; kb < 8; ++kb) s[kb] = p[kb] * 0.125f;

    #pragma unroll
    for (int j = 0; j < 8; ++j) {
        int r = 0;
        #pragma unroll
        for (int i = 0; i < 8; ++i)
            r += (s[i] < s[j]) || (s[i] == s[j] && i < j);
        mv[j] = (r >= 4) ? 1.0f : 0.0f;
    }
    if (lane < 8) {
        w_ws[(long)b * 8 + lane] = sigf(s[lane]);
        mblk[(long)b * 8 + lane] = mv[lane];
    }
    #pragma unroll
    for (int it = 0; it < 32; ++it) {
        int idx = it * 64 + lane;
        mask_out[(long)b * 2048 + idx] = mv[idx >> 8];
    }
}

// ---------------------------------------------------------------------------
// MFMA gates + LSTM. Also emits bf16 copy of h_new (hnb) for the qkv GEMM.
// ---------------------------------------------------------------------------
__global__ __launch_bounds__(256, 2) void gates_mfma_kernel(
    const unsigned short* __restrict__ Ab,   // v1b  [4096][1024]
    const unsigned short* __restrict__ Hb,   // hxb  [4096][2048]
    const unsigned short* __restrict__ Wihb, // [8][1024][1024]
    const unsigned short* __restrict__ Whhb, // [8][1024][256]
    const float* __restrict__ b_ih, const float* __restrict__ b_hh,
    const float* __restrict__ w_ws, const float* __restrict__ cx,
    float* __restrict__ h_out, float* __restrict__ c_out,
    unsigned short* __restrict__ hn_b)
{
    const int m0 = blockIdx.x * 128;
    const int j0 = blockIdx.y * 64;
    const int kb = blockIdx.z;

    __shared__ unsigned short As[128 * 64];
    __shared__ unsigned short Bs[256 * 64];
    __shared__ float wv[128];

    const int t = threadIdx.x;
    const int wid = t >> 6;
    const int l = t & 63;
    const int l15 = l & 15;
    const int l4 = l >> 4;
    const int wm = wid >> 1;
    const int wj = wid & 1;

    if (t < 128) wv[t] = w_ws[(long)(m0 + t) * 8 + kb];

    f32x4 acc[4][8];
    #pragma unroll
    for (int m = 0; m < 4; ++m)
        #pragma unroll
        for (int n = 0; n < 8; ++n)
            acc[m][n] = (f32x4){0.f, 0.f, 0.f, 0.f};

    auto stage = [&](const unsigned short* Aptr, long lda,
                     const unsigned short* Bptr, long ldb, int k0) {
        #pragma unroll
        for (int s = 0; s < 4; ++s) {
            int ci = (wid * 4 + s) * 64 + l;
            int r = ci >> 3, cs = ci & 7;
            const unsigned short* g = Aptr + (long)r * lda + k0 + ((cs ^ (r & 7)) << 3);
            gload16(g, &As[ci * 8]);
        }
        #pragma unroll
        for (int s = 0; s < 8; ++s) {
            int ci = (wid * 8 + s) * 64 + l;
            int rn = ci >> 3, cs = ci & 7;
            int sg = rn >> 6, jl = rn & 63;
            const unsigned short* g = Bptr + (long)(sg * 256 + j0 + jl) * ldb + k0
                                      + ((cs ^ (rn & 7)) << 3);
            gload16(g, &Bs[ci * 8]);
        }
    };

    auto compute = [&]() {
        #pragma unroll
        for (int kh = 0; kh < 2; ++kh) {
            bf16x8 af[4];
            #pragma unroll
            for (int m = 0; m < 4; ++m) {
                int r = wm * 64 + m * 16 + l15;
                int c = kh * 4 + l4;
                af[m] = *reinterpret_cast<const bf16x8*>(&As[r * 64 + ((c ^ (r & 7)) << 3)]);
            }
            #pragma unroll
            for (int sg = 0; sg < 4; ++sg) {
                #pragma unroll
                for (int jf = 0; jf < 2; ++jf) {
                    int rn = sg * 64 + wj * 32 + jf * 16 + l15;
                    int c = kh * 4 + l4;
                    bf16x8 bf = *reinterpret_cast<const bf16x8*>(
                        &Bs[rn * 64 + ((c ^ (rn & 7)) << 3)]);
                    #pragma unroll
                    for (int m = 0; m < 4; ++m)
                        acc[m][sg * 2 + jf] = __builtin_amdgcn_mfma_f32_16x16x32_bf16(
                            af[m], bf, acc[m][sg * 2 + jf], 0, 0, 0);
                }
            }
        }
    };

    {
        const unsigned short* A1 = Ab + (long)m0 * 1024;
        const unsigned short* B1 = Wihb + (long)kb * 1024 * 1024;
        for (int k0 = 0; k0 < 1024; k0 += 64) {
            stage(A1, 1024, B1, 1024, k0);
            __syncthreads();
            compute();
            __syncthreads();
        }
    }

    {
        float wsc[4][4];
        #pragma unroll
        for (int m = 0; m < 4; ++m)
            #pragma unroll
            for (int r = 0; r < 4; ++r)
                wsc[m][r] = wv[wm * 64 + m * 16 + l4 * 4 + r];
        #pragma unroll
        for (int m = 0; m < 4; ++m)
            #pragma unroll
            for (int n = 0; n < 8; ++n)
                #pragma unroll
                for (int r = 0; r < 4; ++r)
                    acc[m][n][r] *= wsc[m][r];
    }

    {
        const unsigned short* A2 = Hb + (long)m0 * 2048 + kb * 256;
        const unsigned short* B2 = Whhb + (long)kb * 1024 * 256;
        for (int k0 = 0; k0 < 256; k0 += 64) {
            stage(A2, 2048, B2, 256, k0);
            __syncthreads();
            compute();
            __syncthreads();
        }
    }

    #pragma unroll
    for (int jf = 0; jf < 2; ++jf) {
        const int jcol = j0 + wj * 32 + jf * 16 + l15;
        const long bb = (long)kb * 1024 + jcol;
        const float bI = b_ih[bb] + b_hh[bb];
        const float bF = b_ih[bb + 256] + b_hh[bb + 256];
        const float bG = b_ih[bb + 512] + b_hh[bb + 512];
        const float bO = b_ih[bb + 768] + b_hh[bb + 768];
        #pragma unroll
        for (int m = 0; m < 4; ++m) {
            #pragma unroll
            for (int r = 0; r < 4; ++r) {
                const long row = m0 + wm * 64 + m * 16 + l4 * 4 + r;
                const long idx = row * 2048 + kb * 256 + jcol;
                const float ig = acc[m][0 + jf][r] + bI;
                const float fg = acc[m][2 + jf][r] + bF;
                const float gg = acc[m][4 + jf][r] + bG;
                const float og = acc[m][6 + jf][r] + bO;
                const float co = cx[idx];
                const float cn = sigf(fg) * co + sigf(ig) * tanhf(gg);
                const float hn = sigf(og) * tanhf(cn);
                h_out[idx] = hn;
                c_out[idx] = cn;
                hn_b[idx] = f2bf(hn);
            }
        }
    }
}

// ---------------------------------------------------------------------------
// Inner NBxNB attention over bf16 qkv [4096][1536] (per kb: q|k|v 64 each).
// ---------------------------------------------------------------------------
__global__ __launch_bounds__(256) void attn_m2_kernel(
    const unsigned short* __restrict__ qkv, float* __restrict__ o)
{
    const int tid = blockIdx.x * 256 + threadIdx.x;
    const int b = tid >> 5;
    const int qkb = (tid >> 2) & 7;
    const int h = tid & 3;
    const unsigned short* base = qkv + (long)b * 1536;

    float qv[16];
    {
        const unsigned short* qp = base + qkb * 192 + h * 16;
        #pragma unroll
        for (int e = 0; e < 16; ++e) qv[e] = bf2f(qp[e]);
    }

    float sc[8];
    float mx = -1e30f;
    #pragma unroll
    for (int kk = 0; kk < 8; ++kk) {
        const unsigned short* kp = base + kk * 192 + 64 + h * 16;
        float s = 0.f;
        #pragma unroll
        for (int e = 0; e < 16; ++e) s += qv[e] * bf2f(kp[e]);
        s *= 0.25f;
        sc[kk] = s;
        mx = fmaxf(mx, s);
    }
    float den = 0.f;
    #pragma unroll
    for (int kk = 0; kk < 8; ++kk) { sc[kk] = expf(sc[kk] - mx); den += sc[kk]; }
    const float inv = 1.0f / den;

    float ov[16] = {};
    #pragma unroll
    for (int kk = 0; kk < 8; ++kk) {
        const float pw = sc[kk] * inv;
        const unsigned short* vp = base + kk * 192 + 128 + h * 16;
        #pragma unroll
        for (int e = 0; e < 16; ++e) ov[e] += pw * bf2f(vp[e]);
    }
    float* op = o + (long)b * 512 + qkb * 64 + h * 16;
    #pragma unroll
    for (int e = 0; e < 16; ++e) op[e] = ov[e];
}

// ---------------------------------------------------------------------------
// Epilogue: att_out, h_final, masked blend (unchanged from round 3).
// ---------------------------------------------------------------------------
__global__ __launch_bounds__(256) void final_kernel2(
    const float* __restrict__ o,
    const float* __restrict__ Wtg, const float* __restrict__ Wtf,
    const float* __restrict__ gate_b, const float* __restrict__ fc_b,
    const float* __restrict__ mblk,
    const float* __restrict__ hx, const float* __restrict__ cx,
    float* __restrict__ h_out, float* __restrict__ c_out)
{
    __shared__ float osh[4][512];
    const int w = threadIdx.x >> 6;
    const int l = threadIdx.x & 63;
    const int b = blockIdx.x * 4 + w;
    const int j = l * 4;

    {
        const float4* op = (const float4*)(o + (long)b * 512);
        *(float4*)&osh[w][l * 8]     = op[l * 2];
        *(float4*)&osh[w][l * 8 + 4] = op[l * 2 + 1];
    }
    __builtin_amdgcn_s_waitcnt(0);

    float accg[8][4] = {};
    float accf[8][4] = {};

    #pragma unroll 4
    for (int e = 0; e < 64; ++e) {
        const float4 wg = *(const float4*)&Wtg[e * 256 + j];
        const float4 wf = *(const float4*)&Wtf[e * 256 + j];
        #pragma unroll
        for (int kb = 0; kb < 8; ++kb) {
            const float ov = osh[w][kb * 64 + e];
            accg[kb][0] += ov * wg.x; accg[kb][1] += ov * wg.y;
            accg[kb][2] += ov * wg.z; accg[kb][3] += ov * wg.w;
            accf[kb][0] += ov * wf.x; accf[kb][1] += ov * wf.y;
            accf[kb][2] += ov * wf.z; accf[kb][3] += ov * wf.w;
        }
    }

    const float4 gb = *(const float4*)&gate_b[j];
    const float4 fb = *(const float4*)&fc_b[j];

    #pragma unroll
    for (int kb = 0; kb < 8; ++kb) {
        const long idx = (long)b * 2048 + kb * 256 + j;
        const float m = mblk[(long)b * 8 + kb];
        float4 hn = *(const float4*)&h_out[idx];
        float4 cn = *(const float4*)&c_out[idx];
        const float4 hxv = *(const float4*)&hx[idx];
        const float4 cxv = *(const float4*)&cx[idx];
        float att0 = sigf(accg[kb][0] + gb.x) * tanhf(accf[kb][0] + fb.x);
        float att1 = sigf(accg[kb][1] + gb.y) * tanhf(accf[kb][1] + fb.y);
        float att2 = sigf(accg[kb][2] + gb.z) * tanhf(accf[kb][2] + fb.z);
        float att3 = sigf(accg[kb][3] + gb.w) * tanhf(accf[kb][3] + fb.w);
        hn.x += att0; hn.y += att1; hn.z += att2; hn.w += att3;
        if (m == 0.0f) { hn = hxv; cn = cxv; }
        *(float4*)&h_out[idx] = hn;
        *(float4*)&c_out[idx] = cn;
    }
}

// ---------------------------------------------------------------------------
extern "C" void kernel_launch(void* const* d_in, const int* in_sizes, int n_in,
                              void* d_out, int out_size, void* d_ws, size_t ws_size,
                              hipStream_t stream) {
    const float* inp    = (const float*)d_in[0];
    const float* hx     = (const float*)d_in[1];
    const float* cx     = (const float*)d_in[2];
    const float* Wq_i   = (const float*)d_in[3];
    const float* Wk_i   = (const float*)d_in[4];
    const float* Wv_i   = (const float*)d_in[5];
    const float* Wq_m   = (const float*)d_in[6];
    const float* Wk_m   = (const float*)d_in[7];
    const float* Wv_m   = (const float*)d_in[8];
    const float* fc_w   = (const float*)d_in[9];
    const float* fc_b   = (const float*)d_in[10];
    const float* gate_w = (const float*)d_in[11];
    const float* gate_b = (const float*)d_in[12];
    const float* Wih    = (const float*)d_in[13];
    const float* Whh    = (const float*)d_in[14];
    const float* b_ih   = (const float*)d_in[15];
    const float* b_hh   = (const float*)d_in[16];

    float* out      = (float*)d_out;
    float* h_out    = out;
    float* c_out    = out + (long)B_SZ * 2048;
    float* mask_out = out + (long)2 * B_SZ * 2048;

    // ---- workspace layout with lifetime aliasing (~63.3 MB) ----
    float* ws   = (float*)d_ws;
    float* w_ws = ws;                                       // B*8 f32
    float* mblk = w_ws + (long)B_SZ * 8;                    // B*8 f32
    unsigned short* v1b = (unsigned short*)(mblk + (long)B_SZ * 8);  // B*1024
    unsigned short* hxb = v1b + (long)B_SZ * 1024;                   // B*2048
    // R region: hnb | Wihb | Whhb  (37.75 MB)
    unsigned short* hnb  = hxb + (long)B_SZ * 2048;         // B*2048 (live: gates -> qkv gemm)
    unsigned short* Wihb = hnb + (long)B_SZ * 2048;         // 8M u16 (live: f2bf -> gates)
    unsigned short* Whhb = Wihb + (long)8 * 1024 * 1024;    // 2M u16 (live: f2bf -> gates)
    float* Wt_g = (float*)(Whhb + (long)8 * 1024 * 256);    // 64*256
    float* Wt_f = Wt_g + 64 * 256;                          // 64*256
    // early aliases inside Wihb span (dead before f2bf(Wih)):
    float* k1 = (float*)Wihb;                               // B*64 f32
    float* q  = k1 + (long)B_SZ * 64;                       // B*512 f32
    unsigned short* inpb = (unsigned short*)(q + (long)B_SZ * 512);  // B*512 bf16
    unsigned short* Wvb  = inpb + (long)B_SZ * 512;         // 1024*512 bf16
    // late aliases (after gates):
    unsigned short* Wqkvb = Wihb;                           // 8*192*256 bf16 (over dead Wihb)
    unsigned short* qkvb  = hxb;                            // B*1536 bf16 (over dead hxb)
    float* o = (float*)v1b;                                 // B*512 f32 (over dead v1b)

    // transposed epilogue weights
    wtrans_kernel<<<dim3(64), 256, 0, stream>>>(gate_w, fc_w, Wt_g, Wt_f);
    // hx -> bf16, inp -> bf16
    f2bf_kernel<<<dim3(4096), 256, 0, stream>>>(
        (const float4*)hx, (u16x8*)hxb, (long)B_SZ * 2048 / 8);
    f2bf_kernel<<<dim3(1024), 256, 0, stream>>>(
        (const float4*)inp, (u16x8*)inpb, (long)B_SZ * 512 / 8);
    // k1 = inp @ Wk_i[1]  (f32, mask-critical)
    gemm_f32<<<dim3(1, 64, 1), 256, 0, stream>>>(
        inp, Wk_i + (long)NINP * 64, k1, NINP, NINP, 64, 64, 0, 0, 0);
    // q[b,kb,:] = hx_block @ Wq_i[kb]  (f32, mask-critical)
    gemm_f32<<<dim3(1, 64, 8), 256, 0, stream>>>(
        hx, Wq_i, q, BSZ, NHID, 64, 512, 256, (long)BSZ * 64, 64);
    // Wv_i[1] -> transposed bf16
    wv_trans_kernel<<<dim3(32, 16), 256, 0, stream>>>(
        Wv_i + (long)NINP * ATT_OUT, Wvb);
    // v1 = inp @ Wv_i[1] via MFMA -> bf16
    gemm_mfma<1><<<dim3(32, 16, 1), 256, 0, stream>>>(
        inpb, Wvb, v1b, 512, 512, 512, 1024, 0, 0, 0);
    // s1, w, mblk, mask (kills k1,q)
    s1_mask_kernel<<<dim3(B_SZ / 4), 256, 0, stream>>>(q, k1, w_ws, mblk, mask_out);
    // weights -> bf16 (overwrites early aliases; v1 gemm already done)
    f2bf_kernel<<<dim3(4096), 256, 0, stream>>>(
        (const float4*)Wih, (u16x8*)Wihb, (long)8 * 1024 * 1024 / 8);
    f2bf_kernel<<<dim3(1024), 256, 0, stream>>>(
        (const float4*)Whh, (u16x8*)Whhb, (long)8 * 1024 * 256 / 8);
    // gates + LSTM (MFMA) -> h_new, c_new, hnb
    gates_mfma_kernel<<<dim3(B_SZ / 128, 4, 8), 256, 0, stream>>>(
        v1b, hxb, Wihb, Whhb, b_ih, b_hh, w_ws, cx, h_out, c_out, hnb);
    // W{q,k,v}_m -> concat transposed bf16 (over dead Wihb)
    qkvw_kernel<<<dim3(1536), 256, 0, stream>>>(Wq_m, Wk_m, Wv_m, Wqkvb);
    // qkv = h_new_block @ W*_m (batched MFMA) -> bf16 [4096][1536]
    gemm_mfma<1><<<dim3(32, 3, 8), 256, 0, stream>>>(
        hnb, Wqkvb, qkvb, 256, 2048, 256, 1536, 256, (long)192 * 256, 192);
    // inner attention -> o
    attn_m2_kernel<<<dim3(B_SZ * 32 / 256), 256, 0, stream>>>(qkvb, o);
    // epilogue
    final_kernel2<<<dim3(B_SZ / 4), 256, 0, stream>>>(
        o, Wt_g, Wt_f, gate_b, fc_b, mblk, hx, cx, h_out, c_out);
}

// Round 5
// 267.671 us; speedup vs baseline: 13.5661x; 1.2052x over previous
//
#include <hip/hip_runtime.h>
#include <hip/hip_bf16.h>

// BlocksCore forward. Round 5: tail attack — fused f32 qk1 GEMM (mask-critical),
// MFMA attn-final epilogue, c-blend folded into gates.

#define B_SZ 4096
#define NINP 512
#define NHID 2048
#define NB 8
#define BSZ 256
#define ATT_OUT 1024

typedef __attribute__((ext_vector_type(8))) short bf16x8;
typedef __attribute__((ext_vector_type(8))) unsigned short u16x8;
typedef __attribute__((ext_vector_type(4))) float f32x4;

__device__ __forceinline__ float sigf(float x) { return 1.0f / (1.0f + expf(-x)); }

__device__ __forceinline__ unsigned short f2bf(float x) {
    unsigned u = __float_as_uint(x);
    unsigned r = (u + 0x7fff + ((u >> 16) & 1)) >> 16;
    return (unsigned short)r;
}
__device__ __forceinline__ float bf2f(unsigned short u) {
    return __uint_as_float((unsigned)u << 16);
}

// async global->LDS, 16B per lane. LDS dest must be wave-uniform base + lane*16.
__device__ __forceinline__ void gload16(const void* g, void* l) {
    __builtin_amdgcn_global_load_lds(
        (const __attribute__((address_space(1))) unsigned int*)(unsigned long long)g,
        (__attribute__((address_space(3))) unsigned int*)(unsigned int)(unsigned long long)l,
        16, 0, 0);
}

// ---------------------------------------------------------------------------
// f32 -> bf16 elementwise convert (8 elems/thread)
// ---------------------------------------------------------------------------
__global__ __launch_bounds__(256) void f2bf_kernel(
    const float4* __restrict__ in, u16x8* __restrict__ out, long n8)
{
    long i = (long)blockIdx.x * 256 + threadIdx.x;
    if (i >= n8) return;
    float4 a = in[i * 2], b = in[i * 2 + 1];
    u16x8 v;
    v[0] = f2bf(a.x); v[1] = f2bf(a.y); v[2] = f2bf(a.z); v[3] = f2bf(a.w);
    v[4] = f2bf(b.x); v[5] = f2bf(b.y); v[6] = f2bf(b.z); v[7] = f2bf(b.w);
    out[i] = v;
}

// ---------------------------------------------------------------------------
// Wv_i[1] [512][1024] f32 -> Wvb [1024][512] bf16 (LDS tile transpose).
// ---------------------------------------------------------------------------
__global__ __launch_bounds__(256) void wv_trans_kernel(
    const float* __restrict__ src, unsigned short* __restrict__ dst)
{
    __shared__ float tile[32][33];
    const int n0 = blockIdx.x * 32;
    const int k0 = blockIdx.y * 32;
    const int tx = threadIdx.x & 31;
    const int ty = threadIdx.x >> 5;
    #pragma unroll
    for (int r = 0; r < 4; ++r)
        tile[ty + r * 8][tx] = src[(long)(k0 + ty + r * 8) * 1024 + n0 + tx];
    __syncthreads();
    #pragma unroll
    for (int r = 0; r < 4; ++r)
        dst[(long)(n0 + ty + r * 8) * 512 + k0 + tx] = f2bf(tile[tx][ty + r * 8]);
}

// ---------------------------------------------------------------------------
// Wq_m/Wk_m/Wv_m [8][256][64] f32 -> Wqkvb [8][192][256] bf16 (n-major concat).
// ---------------------------------------------------------------------------
__global__ __launch_bounds__(256) void qkvw_kernel(
    const float* __restrict__ Wq, const float* __restrict__ Wk,
    const float* __restrict__ Wv, unsigned short* __restrict__ out)
{
    int idx = blockIdx.x * 256 + threadIdx.x;      // 0..393215
    int k = idx & 255;
    int n = (idx >> 8) % 192;
    int kb = idx / (192 * 256);
    const float* src = (n < 64) ? Wq : (n < 128) ? Wk : Wv;
    int nn = n & 63;
    out[idx] = f2bf(src[(long)kb * 16384 + k * 64 + nn]);
}

// ---------------------------------------------------------------------------
// gate_w/fc_w [256][64] f32 -> Wgfb [512][64] bf16 (rows 0-255 gate, 256-511 fc)
// ---------------------------------------------------------------------------
__global__ __launch_bounds__(256) void wgf_pack_kernel(
    const float* __restrict__ gw, const float* __restrict__ fw,
    unsigned short* __restrict__ out)
{
    int t = blockIdx.x * 256 + threadIdx.x;   // 0..32767
    if (t >= 32768) return;
    out[t] = f2bf((t < 16384) ? gw[t] : fw[t - 16384]);
}

// ---------------------------------------------------------------------------
// Fused f32 GEMMs for the mask-critical path.
// role = blockIdx.y: 0..7 -> q[b, kb=role, :] = hx_blk @ Wq_i[kb]  (K=256)
//                    8    -> k1 = inp @ Wk_i[1]                    (K=512)
// Tile 32(M) x 64(N), BK=32, 256 threads, 2x4 outputs/thread.
// Sequential-k accumulation identical to prior rounds (ordering-safe).
// ---------------------------------------------------------------------------
__global__ __launch_bounds__(256) void qk1_kernel(
    const float* __restrict__ inp, const float* __restrict__ hx,
    const float* __restrict__ Wk1, const float* __restrict__ Wq,
    float* __restrict__ k1, float* __restrict__ q)
{
    const int role = blockIdx.y;
    const int m0 = blockIdx.x * 32;
    const float* A; long lda; const float* Bw; int K; float* C; int ldc;
    if (role == 8) {
        A = inp + (long)m0 * 512; lda = 512; Bw = Wk1; K = 512;
        C = k1 + (long)m0 * 64; ldc = 64;
    } else {
        A = hx + (long)m0 * 2048 + role * 256; lda = 2048;
        Bw = Wq + (long)role * 256 * 64; K = 256;
        C = q + (long)m0 * 512 + role * 64; ldc = 512;
    }

    __shared__ float As[32][33];
    __shared__ float Bs[32][64];

    const int t = threadIdx.x;
    const int ty = t >> 4;   // 0..15 (2 rows each)
    const int tx = t & 15;   // 0..15 (4 cols each)

    float acc[2][4] = {};

    for (int k0 = 0; k0 < K; k0 += 32) {
        {
            int m = t >> 3, kk = (t & 7) << 2;
            float4 av = *reinterpret_cast<const float4*>(&A[(long)m * lda + k0 + kk]);
            As[m][kk] = av.x; As[m][kk + 1] = av.y;
            As[m][kk + 2] = av.z; As[m][kk + 3] = av.w;
        }
        #pragma unroll
        for (int u = 0; u < 2; ++u) {
            int f = t + 256 * u;
            int kr = f >> 4, c = (f & 15) << 2;
            float4 bv = *reinterpret_cast<const float4*>(&Bw[(long)(k0 + kr) * 64 + c]);
            *reinterpret_cast<float4*>(&Bs[kr][c]) = bv;
        }
        __syncthreads();
        #pragma unroll
        for (int kk = 0; kk < 32; ++kk) {
            float a0 = As[ty * 2][kk];
            float a1 = As[ty * 2 + 1][kk];
            float4 bv = *reinterpret_cast<const float4*>(&Bs[kk][tx * 4]);
            acc[0][0] += a0 * bv.x; acc[0][1] += a0 * bv.y;
            acc[0][2] += a0 * bv.z; acc[0][3] += a0 * bv.w;
            acc[1][0] += a1 * bv.x; acc[1][1] += a1 * bv.y;
            acc[1][2] += a1 * bv.z; acc[1][3] += a1 * bv.w;
        }
        __syncthreads();
    }
    #pragma unroll
    for (int i = 0; i < 2; ++i) {
        float4 v = {acc[i][0], acc[i][1], acc[i][2], acc[i][3]};
        *reinterpret_cast<float4*>(&C[(long)(ty * 2 + i) * ldc + tx * 4]) = v;
    }
}

// ---------------------------------------------------------------------------
// Generic bf16 MFMA GEMM: C[m,n] = sum_k A[m,k] * B[n,k]  (B is N x K).
// Tile 128(M) x 64(N), BK=64, 4 waves (2M x 2N). bf16 output.
// ---------------------------------------------------------------------------
__global__ __launch_bounds__(256, 2) void gemm_mfma_bf(
    const unsigned short* __restrict__ A,
    const unsigned short* __restrict__ Bm,
    unsigned short* __restrict__ Cv,
    int K, int lda, int ldb, int ldc,
    long aOffZ, long bOffZ, long cOffZ)
{
    const int m0 = blockIdx.x * 128;
    const int n0 = blockIdx.y * 64;
    const int z = blockIdx.z;
    A += (long)z * aOffZ;
    Bm += (long)z * bOffZ;

    __shared__ unsigned short As[128 * 64];
    __shared__ unsigned short Bs[64 * 64];

    const int t = threadIdx.x;
    const int wid = t >> 6;
    const int l = t & 63;
    const int l15 = l & 15;
    const int l4 = l >> 4;
    const int wm = wid >> 1;
    const int wn = wid & 1;

    f32x4 acc[4][2];
    #pragma unroll
    for (int m = 0; m < 4; ++m)
        #pragma unroll
        for (int n = 0; n < 2; ++n)
            acc[m][n] = (f32x4){0.f, 0.f, 0.f, 0.f};

    for (int k0 = 0; k0 < K; k0 += 64) {
        #pragma unroll
        for (int s = 0; s < 4; ++s) {
            int ci = (wid * 4 + s) * 64 + l;
            int r = ci >> 3, cs = ci & 7;
            gload16(A + (long)(m0 + r) * lda + k0 + ((cs ^ (r & 7)) << 3), &As[ci * 8]);
        }
        #pragma unroll
        for (int s = 0; s < 2; ++s) {
            int ci = (wid * 2 + s) * 64 + l;
            int rn = ci >> 3, cs = ci & 7;
            gload16(Bm + (long)(n0 + rn) * ldb + k0 + ((cs ^ (rn & 7)) << 3), &Bs[ci * 8]);
        }
        __syncthreads();
        #pragma unroll
        for (int kh = 0; kh < 2; ++kh) {
            bf16x8 af[4];
            #pragma unroll
            for (int m = 0; m < 4; ++m) {
                int r = wm * 64 + m * 16 + l15;
                int c = kh * 4 + l4;
                af[m] = *reinterpret_cast<const bf16x8*>(&As[r * 64 + ((c ^ (r & 7)) << 3)]);
            }
            #pragma unroll
            for (int nf = 0; nf < 2; ++nf) {
                int rn = wn * 32 + nf * 16 + l15;
                int c = kh * 4 + l4;
                bf16x8 bf = *reinterpret_cast<const bf16x8*>(
                    &Bs[rn * 64 + ((c ^ (rn & 7)) << 3)]);
                #pragma unroll
                for (int m = 0; m < 4; ++m)
                    acc[m][nf] = __builtin_amdgcn_mfma_f32_16x16x32_bf16(
                        af[m], bf, acc[m][nf], 0, 0, 0);
            }
        }
        __syncthreads();
    }

    #pragma unroll
    for (int nf = 0; nf < 2; ++nf) {
        const int ccol = n0 + wn * 32 + nf * 16 + l15;
        #pragma unroll
        for (int m = 0; m < 4; ++m) {
            #pragma unroll
            for (int r = 0; r < 4; ++r) {
                const long crow = m0 + wm * 64 + m * 16 + l4 * 4 + r;
                Cv[(long)z * cOffZ + crow * ldc + ccol] = f2bf(acc[m][nf][r]);
            }
        }
    }
}

// ---------------------------------------------------------------------------
// s1 / sigmoid weight / exact top-k mask (f32, mask-critical).
// ---------------------------------------------------------------------------
__global__ __launch_bounds__(256) void s1_mask_kernel(
    const float* __restrict__ q, const float* __restrict__ k1,
    float* __restrict__ w_ws, float* __restrict__ mblk,
    float* __restrict__ mask_out)
{
    const int wave = threadIdx.x >> 6;
    const int lane = threadIdx.x & 63;
    const int b = blockIdx.x * 4 + wave;

    float p[8];
    const float kv = k1[(long)b * 64 + lane];
    #pragma unroll
    for (int kb = 0; kb < 8; ++kb)
        p[kb] = q[(long)b * 512 + kb * 64 + lane] * kv;

    #pragma unroll
    for (int off = 1; off < 64; off <<= 1) {
        #pragma unroll
        for (int kb = 0; kb < 8; ++kb) p[kb] += __shfl_xor(p[kb], off);
    }

    float s[8], mv[8];
    #pragma unroll
    for (int kb = 0; kb < 8; ++kb) s[kb] = p[kb] * 0.125f;

    #pragma unroll
    for (int j = 0; j < 8; ++j) {
        int r = 0;
        #pragma unroll
        for (int i = 0; i < 8; ++i)
            r += (s[i] < s[j]) || (s[i] == s[j] && i < j);
        mv[j] = (r >= 4) ? 1.0f : 0.0f;
    }
    if (lane < 8) {
        w_ws[(long)b * 8 + lane] = sigf(s[lane]);
        mblk[(long)b * 8 + lane] = mv[lane];
    }
    #pragma unroll
    for (int it = 0; it < 32; ++it) {
        int idx = it * 64 + lane;
        mask_out[(long)b * 2048 + idx] = mv[idx >> 8];
    }
}

// ---------------------------------------------------------------------------
// MFMA gates + LSTM. Emits h_new (f32 + bf16) and mask-blended c_out.
// ---------------------------------------------------------------------------
__global__ __launch_bounds__(256, 2) void gates_mfma_kernel(
    const unsigned short* __restrict__ Ab,   // v1b  [4096][1024]
    const unsigned short* __restrict__ Hb,   // hxb  [4096][2048]
    const unsigned short* __restrict__ Wihb, // [8][1024][1024]
    const unsigned short* __restrict__ Whhb, // [8][1024][256]
    const float* __restrict__ b_ih, const float* __restrict__ b_hh,
    const float* __restrict__ w_ws, const float* __restrict__ mblk,
    const float* __restrict__ cx,
    float* __restrict__ h_out, float* __restrict__ c_out,
    unsigned short* __restrict__ hn_b)
{
    const int m0 = blockIdx.x * 128;
    const int j0 = blockIdx.y * 64;
    const int kb = blockIdx.z;

    __shared__ unsigned short As[128 * 64];
    __shared__ unsigned short Bs[256 * 64];
    __shared__ float wv[128];
    __shared__ float mbs[128];

    const int t = threadIdx.x;
    const int wid = t >> 6;
    const int l = t & 63;
    const int l15 = l & 15;
    const int l4 = l >> 4;
    const int wm = wid >> 1;
    const int wj = wid & 1;

    if (t < 128) {
        wv[t] = w_ws[(long)(m0 + t) * 8 + kb];
        mbs[t] = mblk[(long)(m0 + t) * 8 + kb];
    }

    f32x4 acc[4][8];
    #pragma unroll
    for (int m = 0; m < 4; ++m)
        #pragma unroll
        for (int n = 0; n < 8; ++n)
            acc[m][n] = (f32x4){0.f, 0.f, 0.f, 0.f};

    auto stage = [&](const unsigned short* Aptr, long lda,
                     const unsigned short* Bptr, long ldb, int k0) {
        #pragma unroll
        for (int s = 0; s < 4; ++s) {
            int ci = (wid * 4 + s) * 64 + l;
            int r = ci >> 3, cs = ci & 7;
            const unsigned short* g = Aptr + (long)r * lda + k0 + ((cs ^ (r & 7)) << 3);
            gload16(g, &As[ci * 8]);
        }
        #pragma unroll
        for (int s = 0; s < 8; ++s) {
            int ci = (wid * 8 + s) * 64 + l;
            int rn = ci >> 3, cs = ci & 7;
            int sg = rn >> 6, jl = rn & 63;
            const unsigned short* g = Bptr + (long)(sg * 256 + j0 + jl) * ldb + k0
                                      + ((cs ^ (rn & 7)) << 3);
            gload16(g, &Bs[ci * 8]);
        }
    };

    auto compute = [&]() {
        #pragma unroll
        for (int kh = 0; kh < 2; ++kh) {
            bf16x8 af[4];
            #pragma unroll
            for (int m = 0; m < 4; ++m) {
                int r = wm * 64 + m * 16 + l15;
                int c = kh * 4 + l4;
                af[m] = *reinterpret_cast<const bf16x8*>(&As[r * 64 + ((c ^ (r & 7)) << 3)]);
            }
            #pragma unroll
            for (int sg = 0; sg < 4; ++sg) {
                #pragma unroll
                for (int jf = 0; jf < 2; ++jf) {
                    int rn = sg * 64 + wj * 32 + jf * 16 + l15;
                    int c = kh * 4 + l4;
                    bf16x8 bf = *reinterpret_cast<const bf16x8*>(
                        &Bs[rn * 64 + ((c ^ (rn & 7)) << 3)]);
                    #pragma unroll
                    for (int m = 0; m < 4; ++m)
                        acc[m][sg * 2 + jf] = __builtin_amdgcn_mfma_f32_16x16x32_bf16(
                            af[m], bf, acc[m][sg * 2 + jf], 0, 0, 0);
                }
            }
        }
    };

    {
        const unsigned short* A1 = Ab + (long)m0 * 1024;
        const unsigned short* B1 = Wihb + (long)kb * 1024 * 1024;
        for (int k0 = 0; k0 < 1024; k0 += 64) {
            stage(A1, 1024, B1, 1024, k0);
            __syncthreads();
            compute();
            __syncthreads();
        }
    }

    {
        float wsc[4][4];
        #pragma unroll
        for (int m = 0; m < 4; ++m)
            #pragma unroll
            for (int r = 0; r < 4; ++r)
                wsc[m][r] = wv[wm * 64 + m * 16 + l4 * 4 + r];
        #pragma unroll
        for (int m = 0; m < 4; ++m)
            #pragma unroll
            for (int n = 0; n < 8; ++n)
                #pragma unroll
                for (int r = 0; r < 4; ++r)
                    acc[m][n][r] *= wsc[m][r];
    }

    {
        const unsigned short* A2 = Hb + (long)m0 * 2048 + kb * 256;
        const unsigned short* B2 = Whhb + (long)kb * 1024 * 256;
        for (int k0 = 0; k0 < 256; k0 += 64) {
            stage(A2, 2048, B2, 256, k0);
            __syncthreads();
            compute();
            __syncthreads();
        }
    }

    #pragma unroll
    for (int jf = 0; jf < 2; ++jf) {
        const int jcol = j0 + wj * 32 + jf * 16 + l15;
        const long bb = (long)kb * 1024 + jcol;
        const float bI = b_ih[bb] + b_hh[bb];
        const float bF = b_ih[bb + 256] + b_hh[bb + 256];
        const float bG = b_ih[bb + 512] + b_hh[bb + 512];
        const float bO = b_ih[bb + 768] + b_hh[bb + 768];
        #pragma unroll
        for (int m = 0; m < 4; ++m) {
            #pragma unroll
            for (int r = 0; r < 4; ++r) {
                const long row = m0 + wm * 64 + m * 16 + l4 * 4 + r;
                const long idx = row * 2048 + kb * 256 + jcol;
                const float mv = mbs[wm * 64 + m * 16 + l4 * 4 + r];
                const float ig = acc[m][0 + jf][r] + bI;
                const float fg = acc[m][2 + jf][r] + bF;
                const float gg = acc[m][4 + jf][r] + bG;
                const float og = acc[m][6 + jf][r] + bO;
                const float co = cx[idx];
                const float cn = sigf(fg) * co + sigf(ig) * tanhf(gg);
                const float hn = sigf(og) * tanhf(cn);
                h_out[idx] = hn;                          // h_new (blend in final)
                c_out[idx] = (mv != 0.0f) ? cn : co;      // c blended here
                hn_b[idx] = f2bf(hn);
            }
        }
    }
}

// ---------------------------------------------------------------------------
// Inner NBxNB attention over bf16 qkv [4096][1536]; bf16 output ob [32768][64].
// ---------------------------------------------------------------------------
__global__ __launch_bounds__(256) void attn_m2_kernel(
    const unsigned short* __restrict__ qkv, unsigned short* __restrict__ ob)
{
    const int tid = blockIdx.x * 256 + threadIdx.x;
    const int b = tid >> 5;
    const int qkb = (tid >> 2) & 7;
    const int h = tid & 3;
    const unsigned short* base = qkv + (long)b * 1536;

    float qv[16];
    {
        const unsigned short* qp = base + qkb * 192 + h * 16;
        #pragma unroll
        for (int e = 0; e < 16; ++e) qv[e] = bf2f(qp[e]);
    }

    float sc[8];
    float mx = -1e30f;
    #pragma unroll
    for (int kk = 0; kk < 8; ++kk) {
        const unsigned short* kp = base + kk * 192 + 64 + h * 16;
        float s = 0.f;
        #pragma unroll
        for (int e = 0; e < 16; ++e) s += qv[e] * bf2f(kp[e]);
        s *= 0.25f;
        sc[kk] = s;
        mx = fmaxf(mx, s);
    }
    float den = 0.f;
    #pragma unroll
    for (int kk = 0; kk < 8; ++kk) { sc[kk] = expf(sc[kk] - mx); den += sc[kk]; }
    const float inv = 1.0f / den;

    float ov[16] = {};
    #pragma unroll
    for (int kk = 0; kk < 8; ++kk) {
        const float pw = sc[kk] * inv;
        const unsigned short* vp = base + kk * 192 + 128 + h * 16;
        #pragma unroll
        for (int e = 0; e < 16; ++e) ov[e] += pw * bf2f(vp[e]);
    }
    u16x8 r0, r1;
    #pragma unroll
    for (int e = 0; e < 8; ++e) { r0[e] = f2bf(ov[e]); r1[e] = f2bf(ov[e + 8]); }
    unsigned short* op = ob + (long)((b * 8 + qkb) * 64 + h * 16);
    *reinterpret_cast<u16x8*>(op) = r0;
    *reinterpret_cast<u16x8*>(op + 8) = r1;
}

// ---------------------------------------------------------------------------
// MFMA attn-final: g = O@gate_w^T, f = O@fc_w^T (K=64), att = sig(g)*tanh(f),
// h blend. O rows are (b,kb) pairs (M=32768). B-tile holds 64 gate rows + the
// matching 64 fc rows so (g,f) pairs land in-lane.
// ---------------------------------------------------------------------------
__global__ __launch_bounds__(256) void attn_final_kernel(
    const unsigned short* __restrict__ ob,   // [32768][64]
    const unsigned short* __restrict__ Wgfb, // [512][64]: 0-255 gate, 256-511 fc
    const float* __restrict__ gate_b, const float* __restrict__ fc_b,
    const float* __restrict__ mblk,
    const float* __restrict__ hx,
    float* __restrict__ h_out)
{
    const int m0 = blockIdx.x * 128;   // (b,kb)-pair tile
    const int j0 = blockIdx.y * 64;    // j tile

    __shared__ unsigned short As[128 * 64];
    __shared__ unsigned short Bs[128 * 64];

    const int t = threadIdx.x;
    const int wid = t >> 6;
    const int l = t & 63;
    const int l15 = l & 15;
    const int l4 = l >> 4;
    const int wm = wid >> 1;
    const int wn = wid & 1;

    #pragma unroll
    for (int s = 0; s < 4; ++s) {
        int ci = (wid * 4 + s) * 64 + l;
        int r = ci >> 3, cs = ci & 7;
        gload16(ob + (long)(m0 + r) * 64 + ((cs ^ (r & 7)) << 3), &As[ci * 8]);
    }
    #pragma unroll
    for (int s = 0; s < 4; ++s) {
        int ci = (wid * 4 + s) * 64 + l;
        int r = ci >> 3, cs = ci & 7;
        int n = (r < 64) ? (j0 + r) : (256 + j0 + (r - 64));
        gload16(Wgfb + (long)n * 64 + ((cs ^ (r & 7)) << 3), &Bs[ci * 8]);
    }
    __syncthreads();

    f32x4 acc[4][2][2];  // m-frag, nf, {gate,fc}
    #pragma unroll
    for (int m = 0; m < 4; ++m)
        #pragma unroll
        for (int nf = 0; nf < 2; ++nf)
            #pragma unroll
            for (int gf = 0; gf < 2; ++gf)
                acc[m][nf][gf] = (f32x4){0.f, 0.f, 0.f, 0.f};

    #pragma unroll
    for (int kh = 0; kh < 2; ++kh) {
        const int c = kh * 4 + l4;
        bf16x8 af[4];
        #pragma unroll
        for (int m = 0; m < 4; ++m) {
            int r = wm * 64 + m * 16 + l15;
            af[m] = *reinterpret_cast<const bf16x8*>(&As[r * 64 + ((c ^ (r & 7)) << 3)]);
        }
        #pragma unroll
        for (int nf = 0; nf < 2; ++nf) {
            int rg = wn * 32 + nf * 16 + l15;
            bf16x8 bg = *reinterpret_cast<const bf16x8*>(
                &Bs[rg * 64 + ((c ^ (rg & 7)) << 3)]);
            int rf = 64 + rg;
            bf16x8 bfv = *reinterpret_cast<const bf16x8*>(
                &Bs[rf * 64 + ((c ^ (rf & 7)) << 3)]);
            #pragma unroll
            for (int m = 0; m < 4; ++m) {
                acc[m][nf][0] = __builtin_amdgcn_mfma_f32_16x16x32_bf16(
                    af[m], bg, acc[m][nf][0], 0, 0, 0);
                acc[m][nf][1] = __builtin_amdgcn_mfma_f32_16x16x32_bf16(
                    af[m], bfv, acc[m][nf][1], 0, 0, 0);
            }
        }
    }

    #pragma unroll
    for (int nf = 0; nf < 2; ++nf) {
        const int j = j0 + wn * 32 + nf * 16 + l15;
        const float gb = gate_b[j];
        const float fb = fc_b[j];
        #pragma unroll
        for (int m = 0; m < 4; ++m) {
            #pragma unroll
            for (int r = 0; r < 4; ++r) {
                const long p = m0 + wm * 64 + m * 16 + l4 * 4 + r;  // (b,kb) pair
                const float g = acc[m][nf][0][r] + gb;
                const float f = acc[m][nf][1][r] + fb;
                const float att = sigf(g) * tanhf(f);
                const long idx = (p >> 3) * 2048 + (p & 7) * 256 + j;
                const float mv = mblk[p];
                const float hn = h_out[idx] + att;
                h_out[idx] = (mv != 0.0f) ? hn : hx[idx];
            }
        }
    }
}

// ---------------------------------------------------------------------------
extern "C" void kernel_launch(void* const* d_in, const int* in_sizes, int n_in,
                              void* d_out, int out_size, void* d_ws, size_t ws_size,
                              hipStream_t stream) {
    const float* inp    = (const float*)d_in[0];
    const float* hx     = (const float*)d_in[1];
    const float* cx     = (const float*)d_in[2];
    const float* Wq_i   = (const float*)d_in[3];
    const float* Wk_i   = (const float*)d_in[4];
    const float* Wv_i   = (const float*)d_in[5];
    const float* Wq_m   = (const float*)d_in[6];
    const float* Wk_m   = (const float*)d_in[7];
    const float* Wv_m   = (const float*)d_in[8];
    const float* fc_w   = (const float*)d_in[9];
    const float* fc_b   = (const float*)d_in[10];
    const float* gate_w = (const float*)d_in[11];
    const float* gate_b = (const float*)d_in[12];
    const float* Wih    = (const float*)d_in[13];
    const float* Whh    = (const float*)d_in[14];
    const float* b_ih   = (const float*)d_in[15];
    const float* b_hh   = (const float*)d_in[16];

    float* out      = (float*)d_out;
    float* h_out    = out;
    float* c_out    = out + (long)B_SZ * 2048;
    float* mask_out = out + (long)2 * B_SZ * 2048;

    // ---- workspace layout with lifetime aliasing (~63.3 MB) ----
    float* ws   = (float*)d_ws;
    float* w_ws = ws;                                       // B*8 f32
    float* mblk = w_ws + (long)B_SZ * 8;                    // B*8 f32
    unsigned short* v1b = (unsigned short*)(mblk + (long)B_SZ * 8);  // B*1024
    unsigned short* hxb = v1b + (long)B_SZ * 1024;                   // B*2048
    unsigned short* hnb  = hxb + (long)B_SZ * 2048;         // B*2048 (gates -> qkv)
    unsigned short* Wihb = hnb + (long)B_SZ * 2048;         // 8M u16 (f2bf -> gates)
    unsigned short* Whhb = Wihb + (long)8 * 1024 * 1024;    // 2M u16
    unsigned short* Wgfb = Whhb + (long)8 * 1024 * 256;     // 512*64 u16 persistent
    // early aliases inside Wihb span (dead before f2bf(Wih)):
    float* k1 = (float*)Wihb;                               // B*64 f32
    float* q  = k1 + (long)B_SZ * 64;                       // B*512 f32
    unsigned short* inpb = (unsigned short*)(q + (long)B_SZ * 512);  // B*512
    unsigned short* Wvb  = inpb + (long)B_SZ * 512;         // 1024*512
    // late aliases (after gates):
    unsigned short* Wqkvb = Wihb;                           // 8*192*256 (over dead Wihb)
    unsigned short* qkvb  = hxb;                            // B*1536 (over dead hxb)
    unsigned short* ob    = v1b;                            // 32768*64 (over dead v1b)

    // epilogue weights bf16 pack
    wgf_pack_kernel<<<dim3(128), 256, 0, stream>>>(gate_w, fc_w, Wgfb);
    // hx -> bf16, inp -> bf16
    f2bf_kernel<<<dim3(4096), 256, 0, stream>>>(
        (const float4*)hx, (u16x8*)hxb, (long)B_SZ * 2048 / 8);
    f2bf_kernel<<<dim3(1024), 256, 0, stream>>>(
        (const float4*)inp, (u16x8*)inpb, (long)B_SZ * 512 / 8);
    // k1 + q (f32, mask-critical), 1152 blocks
    qk1_kernel<<<dim3(128, 9), 256, 0, stream>>>(
        inp, hx, Wk_i + (long)NINP * 64, Wq_i, k1, q);
    // Wv_i[1] -> transposed bf16
    wv_trans_kernel<<<dim3(32, 16), 256, 0, stream>>>(
        Wv_i + (long)NINP * ATT_OUT, Wvb);
    // v1 = inp @ Wv_i[1] via MFMA -> bf16
    gemm_mfma_bf<<<dim3(32, 16, 1), 256, 0, stream>>>(
        inpb, Wvb, v1b, 512, 512, 512, 1024, 0, 0, 0);
    // s1, w, mblk, mask
    s1_mask_kernel<<<dim3(B_SZ / 4), 256, 0, stream>>>(q, k1, w_ws, mblk, mask_out);
    // weights -> bf16 (clobbers k1/q/inpb/Wvb aliases — all dead)
    f2bf_kernel<<<dim3(4096), 256, 0, stream>>>(
        (const float4*)Wih, (u16x8*)Wihb, (long)8 * 1024 * 1024 / 8);
    f2bf_kernel<<<dim3(1024), 256, 0, stream>>>(
        (const float4*)Whh, (u16x8*)Whhb, (long)8 * 1024 * 256 / 8);
    // gates + LSTM (MFMA) -> h_new, blended c_out, hnb
    gates_mfma_kernel<<<dim3(B_SZ / 128, 4, 8), 256, 0, stream>>>(
        v1b, hxb, Wihb, Whhb, b_ih, b_hh, w_ws, mblk, cx, h_out, c_out, hnb);
    // W{q,k,v}_m -> concat transposed bf16 (over dead Wihb)
    qkvw_kernel<<<dim3(1536), 256, 0, stream>>>(Wq_m, Wk_m, Wv_m, Wqkvb);
    // qkv = h_new_block @ W*_m (batched MFMA) -> bf16
    gemm_mfma_bf<<<dim3(32, 3, 8), 256, 0, stream>>>(
        hnb, Wqkvb, qkvb, 256, 2048, 256, 1536, 256, (long)192 * 256, 192);
    // inner attention -> ob (bf16)
    attn_m2_kernel<<<dim3(B_SZ * 32 / 256), 256, 0, stream>>>(qkvb, ob);
    // MFMA epilogue: att + h blend
    attn_final_kernel<<<dim3(256, 4), 256, 0, stream>>>(
        ob, Wgfb, gate_b, fc_b, mblk, hx, h_out);
}